// Round 7
// baseline (520.739 us; speedup 1.0000x reference)
//
#include <hip/hip_runtime.h>

// ---------------------------------------------------------------------------
// GCN forward, reassociated: per layer h = relu( (A_hat h) W + b ).
// R19: dual-row interleaved gather pipelines.
// R18 post-mortem: resident waves stuck ~10.5/CU across all block shapes;
// phase-B dilution only ~3%; per-edge cost ~300cy => exposed serial latency
// (rowptr->srcs->h0, ~1500cy, 4x per wave) is the remaining layer bottleneck.
// Fix: each 16-lane group processes 2 rows CONCURRENTLY (4-edge batches,
// depth-2 h prefetch, depth-1 srcs prefetch): serial chains/wave 4->2,
// in-flight gather bytes/wave ~2x. VGPR ~120 audited; launch_bounds(256,3)
// caps at ~170 (no spill; R15's lesson). Spill tripwire: WRITE_SIZE >35MB.
// Also: CSR pairs packed to one int (r<<9 | c&511) — halves scatter write
// + fill read traffic.
// Geometry (R18): 256-thread block = 4 independent waves, no barriers,
// wave-private 4.25KB LDS tile, 16 rows/wave. All layers pre-scaled
// (scale_x: S = dinv*h). Epilogue folds bias+relu+output-dinv; layer 4
// fuses the head dot. NOTE: harness delivers int32 edge_index/batch.
// ---------------------------------------------------------------------------

constexpr int D = 128;
constexpr int NGRAPH = 512;
constexpr int CHUNK = 4096;       // edges per scatter block
constexpr int BSH = 9;            // 512 nodes per bucket
constexpr int OP = 136;           // out-tile pitch (ushorts): 272B, 16B-aligned rows

typedef __attribute__((ext_vector_type(8))) short bf16x8;
typedef __attribute__((ext_vector_type(4))) float f32x4;
typedef int i32x4u __attribute__((ext_vector_type(4), aligned(4)));

__device__ __forceinline__ float bf2f(unsigned short b) {
    return __uint_as_float(((unsigned int)b) << 16);
}
__device__ __forceinline__ unsigned short f2bf(float f) {   // round-to-nearest-even
    unsigned int u = __float_as_uint(f);
    u += 0x7FFFu + ((u >> 16) & 1u);
    return (unsigned short)(u >> 16);
}

// merged independent setup: [0,CB) cast x->bf16 | [CB,CB+256) cast W ->
// transposed bf16 Wt | [CB+256, ...) per-chunk bucket histogram.
__global__ __launch_bounds__(256) void setup_all(
        const float4* __restrict__ x4, ushort4* __restrict__ hb, int n4, int CB,
        const float* __restrict__ W, unsigned short* __restrict__ Wt,
        const int* __restrict__ ec, int E, int* __restrict__ bucketCnt) {
    __shared__ int h[256];
    const int t = threadIdx.x;
    const int b = blockIdx.x;
    if (b < CB) {
        int i = b * 256 + t;
        if (i < n4) {
            float4 v = x4[i];
            ushort4 o;
            o.x = f2bf(v.x); o.y = f2bf(v.y); o.z = f2bf(v.z); o.w = f2bf(v.w);
            hb[i] = o;
        }
    } else if (b < CB + 256) {
        int idx = (b - CB) * 256 + t;      // 4*128*128 = 65536 elems
        int i = idx >> 14;
        int rem = idx & 16383;
        int k = rem >> 7, c = rem & 127;
        Wt[(i << 14) + c * 128 + k] = f2bf(W[idx]);
    } else {
        h[t] = 0;
        __syncthreads();
        const int e0 = (b - CB - 256) * CHUNK;
        const int cnt = min(CHUNK, E - e0);
        for (int i = t; i < cnt; i += 256) atomicAdd(&h[ec[e0 + i] >> BSH], 1);
        __syncthreads();
        if (h[t]) atomicAdd(&bucketCnt[t], h[t]);
    }
}

// exclusive scan over 256 bucket counts -> bucketBase, globCursor
__global__ __launch_bounds__(256) void bucket_scan(const int* __restrict__ bucketCnt,
                                                   int* __restrict__ bucketBase,
                                                   int* __restrict__ globCursor) {
    __shared__ int s[256];
    const int t = threadIdx.x;
    int v = bucketCnt[t];
    s[t] = v; __syncthreads();
    for (int off = 1; off < 256; off <<= 1) {
        int x = (t >= off) ? s[t - off] : 0;
        __syncthreads();
        s[t] += x;
        __syncthreads();
    }
    int excl = s[t] - v;
    bucketBase[t] = excl;
    globCursor[t] = excl;
}

// scatter packed (r<<9 | c&511) into bucket-grouped array, LDS-staged
__global__ __launch_bounds__(256) void scatter_pairs(const int* __restrict__ er,
                                                     const int* __restrict__ ec, int E,
                                                     int* __restrict__ globCursor,
                                                     int* __restrict__ pairs) {
    __shared__ int h[256], lbase[256], cur[256], segd[256], s[256];
    __shared__ int stage[CHUNK];
    __shared__ unsigned char sb[CHUNK];
    const int t = threadIdx.x;
    const int e0 = blockIdx.x * CHUNK;
    const int cnt = min(CHUNK, E - e0);

    h[t] = 0;
    __syncthreads();
    for (int i = t; i < cnt; i += 256) atomicAdd(&h[ec[e0 + i] >> BSH], 1);
    __syncthreads();
    int v = h[t];
    s[t] = v; __syncthreads();
    for (int off = 1; off < 256; off <<= 1) {
        int x = (t >= off) ? s[t - off] : 0;
        __syncthreads();
        s[t] += x;
        __syncthreads();
    }
    lbase[t] = s[t] - v;
    cur[t] = s[t] - v;
    segd[t] = atomicAdd(&globCursor[t], v) - lbase[t];
    __syncthreads();
    for (int i = t; i < cnt; i += 256) {
        int c = ec[e0 + i];
        int b = c >> BSH;
        int p = atomicAdd(&cur[b], 1);
        stage[p] = (er[e0 + i] << BSH) | (c & 511);   // packed pair
        sb[p] = (unsigned char)b;
    }
    __syncthreads();
    for (int i = t; i < cnt; i += 256) {
        int b = sb[i];
        pairs[segd[b] + i] = stage[i];
    }
}

// one block per bucket. LDS hist+scan -> rowptr, dinv, slot fill.
__global__ __launch_bounds__(256) void fill_csr(const int* __restrict__ pairs,
                                                const int* __restrict__ bucketBase,
                                                const int* __restrict__ bucketCnt,
                                                int N, int E, int NBUCK,
                                                int* __restrict__ rowptr,
                                                float* __restrict__ dinv,
                                                int* __restrict__ srcs) {
    __shared__ int hist[512], lofs[512], s[256];
    const int t = threadIdx.x;
    const int b = blockIdx.x;
    const int c0 = b << BSH;
    const int base = bucketBase[b];
    const int cnt = bucketCnt[b];
    const int* pp = pairs + base;

    hist[t] = 0; hist[t + 256] = 0;
    __syncthreads();
    for (int i = t; i < cnt; i += 256) atomicAdd(&hist[pp[i] & 511], 1);
    __syncthreads();
    int a0 = hist[2 * t], a1 = hist[2 * t + 1];
    s[t] = a0 + a1; __syncthreads();
    for (int off = 1; off < 256; off <<= 1) {
        int x = (t >= off) ? s[t - off] : 0;
        __syncthreads();
        s[t] += x;
        __syncthreads();
    }
    int excl = s[t] - (a0 + a1);
    lofs[2 * t] = excl;
    lofs[2 * t + 1] = excl + a0;
    __syncthreads();
    const int nn = min(512, N - c0);
    for (int i = t; i < nn; i += 256) {
        rowptr[c0 + i] = base + lofs[i];
        dinv[c0 + i] = rsqrtf((float)hist[i] + 1.0f);
    }
    if (b == NBUCK - 1 && t == 0) rowptr[N] = E;
    __syncthreads();
    for (int i = t; i < cnt; i += 256) {
        int pr = pp[i];
        int p = atomicAdd(&lofs[pr & 511], 1);
        srcs[base + p] = pr >> BSH;
    }
}

// scale the bf16 x-cast by dinv in place (S = dinv * x):
// one uint4 (8 bf16) per thread, 16 uint4 per row.
__global__ __launch_bounds__(256) void scale_x(uint4* __restrict__ Hb0,
                                               const float* __restrict__ dinv,
                                               int nq) {                // nq = N*16
    int i = blockIdx.x * 256 + threadIdx.x;
    if (i >= nq) return;
    float dv = dinv[i >> 4];
    uint4 v = Hb0[i];
    unsigned int* p = (unsigned int*)&v;
#pragma unroll
    for (int k = 0; k < 4; ++k) {
        unsigned int d = p[k];
        unsigned short lo = f2bf(bf2f((unsigned short)(d & 0xFFFFu)) * dv);
        unsigned short hi = f2bf(bf2f((unsigned short)(d >> 16)) * dv);
        p[k] = ((unsigned int)hi << 16) | lo;
    }
    Hb0[i] = v;
}

// ---------------------------------------------------------------------------
// Fused layer: 256-thread block = 4 independent waves (no barriers), each
// owning 16 rows + a private 4.25 KB LDS tile.
// Phase A (dual-row pipelines): group `quad` (16 lanes) processes 2 rows
//   concurrently per sstep (2 ssteps x 2 rows = 4 rows/group). Per row:
//   4-edge batches, h-loads depth-2 (issue h(b+1) before consuming h(b)),
//   srcs depth-1. Tail masked via weight from remaining count; invalid
//   lanes clamp loads to a valid self row. Inputs pre-scaled S = dinv*h.
//   P = dinv[row]*(sum S[src] + S[row]) -> bf16 into xor-swizzled A-tile.
// Phase B: 16x16 MFMA; A-frags from LDS (conflict-free ds_read_b128),
//   W-frags from global (L2-hot). Epilogue folds bias+relu+output-dinv;
//   LDS tile reused as out tile (pitch OP) -> coalesced 16B stores.
//   Layer 4 (writeDots): head dot fused, no Hn write.
// C/D: col=lane&15, row=(lane>>4)*4+reg (verified mapping).
// ---------------------------------------------------------------------------
__global__ __launch_bounds__(256, 3) void layer_fused(
        const int* __restrict__ rowptr, const int* __restrict__ srcs,
        const float* __restrict__ dinv, const unsigned short* __restrict__ H,
        const unsigned short* __restrict__ Wt, const float* __restrict__ bias,
        unsigned short* __restrict__ Hn, float* __restrict__ dots,
        const float* __restrict__ Wl, int N, int writeDots) {
    __shared__ __align__(16) unsigned short u[4][16 * OP];   // 17 KB, wave-private
    const int wave = threadIdx.x >> 6;
    const int lane = threadIdx.x & 63;
    const int row16 = lane & 15;
    const int quad = lane >> 4;
    const int r0 = blockIdx.x * 64 + wave * 16;
    unsigned short* U = u[wave];
    const bf16x8* H8 = (const bf16x8*)H;     // 16 chunks (16B) per row
    const int gl = row16;                    // chunk index this lane owns

    // ---- phase A: aggregate 16 rows (2 per group, 2 at a time) ----
#pragma unroll 1
    for (int ss = 0; ss < 2; ++ss) {
        const int rtA = quad * 4 + ss * 2, rtB = rtA + 1;
        const int rowA = r0 + rtA, rowB = r0 + rtB;
        const int selfA = min(rowA, N - 1), selfB = min(rowB, N - 1);
        const float snA = (rowA < N) ? dinv[rowA] : 0.f;
        const float snB = (rowB < N) ? dinv[rowB] : 0.f;
        int jA = 0, neA = 0, jB = 0, neB = 0;
        if (rowA < N) { jA = rowptr[rowA]; neA = rowptr[rowA + 1] - jA; }
        if (rowB < N) { jB = rowptr[rowB]; neB = rowptr[rowB + 1] - jB; }
        float accA[8], accB[8];
        {   // self terms (pre-scaled; zeroed for invalid rows via sn=0)
            bf16x8 hvA = H8[(size_t)selfA * 16 + gl];
            bf16x8 hvB = H8[(size_t)selfB * 16 + gl];
#pragma unroll
            for (int k = 0; k < 8; ++k) {
                accA[k] = bf2f((unsigned short)hvA[k]);
                accB[k] = bf2f((unsigned short)hvB[k]);
            }
        }
        const int nbA = (neA + 3) >> 2, nbB = (neB + 3) >> 2;
        const int nb = max(nbA, nbB);
        if (nb > 0) {
            i32x4u sAc = {0, 0, 0, 0}, sBc = {0, 0, 0, 0};
            i32x4u sAn = {0, 0, 0, 0}, sBn = {0, 0, 0, 0};
            if (nbA > 0) sAc = *(const i32x4u*)(srcs + jA);
            if (nbB > 0) sBc = *(const i32x4u*)(srcs + jB);
            if (nbA > 1) sAn = *(const i32x4u*)(srcs + jA + 4);
            if (nbB > 1) sBn = *(const i32x4u*)(srcs + jB + 4);
            bf16x8 hA[4], hB[4], hAn[4], hBn[4];
#pragma unroll
            for (int t = 0; t < 4; ++t) {       // issue h(0), both rows
                hA[t] = H8[(size_t)((t < neA) ? sAc[t] : selfA) * 16 + gl];
                hB[t] = H8[(size_t)((t < neB) ? sBc[t] : selfB) * 16 + gl];
            }
#pragma unroll 1
            for (int b = 0; b < nb; ++b) {
                if (b + 1 < nb) {
                    const int bn = (b + 1) * 4;
#pragma unroll
                    for (int t = 0; t < 4; ++t) {   // issue h(b+1), both rows
                        hAn[t] = H8[(size_t)((bn + t < neA) ? sAn[t] : selfA) * 16 + gl];
                        hBn[t] = H8[(size_t)((bn + t < neB) ? sBn[t] : selfB) * 16 + gl];
                    }
                    if (b + 2 < nbA) sAn = *(const i32x4u*)(srcs + jA + (b + 2) * 4);
                    if (b + 2 < nbB) sBn = *(const i32x4u*)(srcs + jB + (b + 2) * 4);
                }
                // consume h(b) for both rows; weights from remaining counts
                const int rb = b * 4;
#pragma unroll
                for (int t = 0; t < 4; ++t) {
                    const float wA = (rb + t < neA) ? 1.f : 0.f;
                    const float wB = (rb + t < neB) ? 1.f : 0.f;
#pragma unroll
                    for (int k = 0; k < 8; ++k) {
                        accA[k] = fmaf(wA, bf2f((unsigned short)hA[t][k]), accA[k]);
                        accB[k] = fmaf(wB, bf2f((unsigned short)hB[t][k]), accB[k]);
                    }
                }
#pragma unroll
                for (int t = 0; t < 4; ++t) { hA[t] = hAn[t]; hB[t] = hBn[t]; }
            }
        }
        // P rows (bf16) -> swizzled A-tile; rows >= N become zeros (sn=0)
        bf16x8 oA, oB;
#pragma unroll
        for (int k = 0; k < 8; ++k) {
            oA[k] = (short)f2bf(snA * accA[k]);
            oB[k] = (short)f2bf(snB * accB[k]);
        }
        *(bf16x8*)(U + rtA * 128 + ((gl ^ rtA) << 3)) = oA;
        *(bf16x8*)(U + rtB * 128 + ((gl ^ rtB) << 3)) = oB;
    }
    // no barrier: wave-private tile; lgkmcnt orders write->read within wave

    // ---- phase B: A fragments, all 4 K-chunks ----
    bf16x8 a0[4];
#pragma unroll
    for (int kc = 0; kc < 4; ++kc) {
        const int ph = (kc * 4 + quad) ^ row16;
        a0[kc] = *(const bf16x8*)(U + row16 * 128 + ph * 8);
    }
    // U is now reused as the out tile (pitch OP); same-wave aliasing ordered

    // dinv of output rows (pre-scale stored features); not needed for dots
    float dv[4];
    if (!writeDots) {
#pragma unroll
        for (int i = 0; i < 4; ++i) {
            int ra = r0 + quad * 4 + i;
            dv[i] = (ra < N) ? dinv[ra] : 0.f;
        }
    }

    float rd[4] = {0.f, 0.f, 0.f, 0.f};
#pragma unroll
    for (int ct = 0; ct < 8; ++ct) {
        const int col = ct * 16 + row16;
        const bf16x8* wc = (const bf16x8*)(Wt + (size_t)col * 128);
        f32x4 acc0 = {0.f, 0.f, 0.f, 0.f};
#pragma unroll
        for (int kc = 0; kc < 4; ++kc) {
            const bf16x8 wf = wc[kc * 4 + quad];
            acc0 = __builtin_amdgcn_mfma_f32_16x16x32_bf16(a0[kc], wf, acc0, 0, 0, 0);
        }
        const float bv = bias[col];
        if (writeDots) {
            const float wl = Wl[col];
#pragma unroll
            for (int i = 0; i < 4; ++i) rd[i] += fmaxf(acc0[i] + bv, 0.f) * wl;
        } else {
#pragma unroll
            for (int i = 0; i < 4; ++i)
                U[(quad * 4 + i) * OP + col] = f2bf(dv[i] * fmaxf(acc0[i] + bv, 0.f));
        }
    }

    if (writeDots) {
#pragma unroll
        for (int m = 1; m < 16; m <<= 1)
#pragma unroll
            for (int i = 0; i < 4; ++i) rd[i] += __shfl_xor(rd[i], m, 64);
        if (row16 == 0) {
#pragma unroll
            for (int i = 0; i < 4; ++i) dots[r0 + quad * 4 + i] = rd[i];
        }
    } else {
        // coalesced readback + store: 256 16B chunks per wave tile, 4/lane
#pragma unroll
        for (int i = 0; i < 4; ++i) {
            int idx = i * 64 + lane;
            int row = idx >> 4, c8 = idx & 15;
            bf16x8 v = *(const bf16x8*)(U + row * OP + c8 * 8);
            *(bf16x8*)(Hn + (size_t)(r0 + row) * 128 + c8 * 8) = v;
        }
    }
}

// one block per graph: binary-search node range in sorted batch, mean, +bl
__global__ __launch_bounds__(256) void pool_graphs(const float* __restrict__ dots,
                                                   const int* __restrict__ batch, int N,
                                                   const float* __restrict__ bl,
                                                   float* __restrict__ out) {
    __shared__ int bounds[2];
    __shared__ float red[4];
    const int g = blockIdx.x;
    const int t = threadIdx.x;
    if (t < 2) {
        int key = g + t;             // lower_bound(batch, key)
        int lo = 0, hi = N;
        while (lo < hi) {
            int mid = (lo + hi) >> 1;
            if (batch[mid] < key) lo = mid + 1; else hi = mid;
        }
        bounds[t] = lo;
    }
    __syncthreads();
    const int lo = bounds[0], hi = bounds[1];
    float s = 0.f;
    for (int i = lo + t; i < hi; i += 256) s += dots[i];
#pragma unroll
    for (int off = 32; off > 0; off >>= 1) s += __shfl_down(s, off, 64);
    if ((t & 63) == 0) red[t >> 6] = s;
    __syncthreads();
    if (t == 0) {
        float tot = red[0] + red[1] + red[2] + red[3];
        int cnt = hi - lo;
        out[g] = tot / (float)(cnt > 0 ? cnt : 1) + bl[0];
    }
}

extern "C" void kernel_launch(void* const* d_in, const int* in_sizes, int n_in,
                              void* d_out, int out_size, void* d_ws, size_t ws_size,
                              hipStream_t stream) {
    const float* x     = (const float*)d_in[0];
    const int*   eidx  = (const int*)d_in[1];    // int32 (harness converts int64)
    const int*   batch = (const int*)d_in[2];
    const float* Ws    = (const float*)d_in[3];
    const float* bs    = (const float*)d_in[4];
    const float* Wl    = (const float*)d_in[5];
    const float* bl    = (const float*)d_in[6];
    (void)n_in; (void)out_size;

    const int N = in_sizes[0] / D;
    const int E = in_sizes[1] / 2;
    const int* er = eidx;       // sources
    const int* ec = eidx + E;   // targets
    const int NBUCK = (N + 511) >> BSH;          // 512-node buckets (<= 256)
    const int NCHUNK = (E + CHUNK - 1) / CHUNK;

    // ---- workspace carve ----
    const int Npad = (N + 127) & ~127;
    const size_t hBytes = (size_t)Npad * D * sizeof(unsigned short); // 25.6 MB bf16
    auto al = [](size_t v) { return (v + 255) & ~(size_t)255; };
    char* base = (char*)d_ws;
    size_t off = 0;

    unsigned short* Hb0 = (unsigned short*)base; off = al(hBytes);
    int* bucketCnt  = (int*)(base + off);
    int* globCursor = bucketCnt + 256;
    off = al(off + 512 * sizeof(int));
    int*   bucketBase = (int*)(base + off);  off = al(off + 256 * sizeof(int));
    float* dinv   = (float*)(base + off);    off = al(off + (size_t)Npad * sizeof(float));
    float* dots   = (float*)(base + off);    off = al(off + (size_t)Npad * sizeof(float));
    int*   rowptr = (int*)(base + off);      off = al(off + (size_t)(Npad + 64) * sizeof(int));
    int*   srcs   = (int*)(base + off);      off = al(off + (size_t)E * sizeof(int) + 64);
    unsigned short* Wt = (unsigned short*)(base + off);   off = al(off + 4 * 128 * 128 * sizeof(unsigned short));

    // second bf16 buffer: in ws if it fits, else reuse x's 51.2 MB input buffer
    // (Npad*256B <= N*512B, so the alias stays in-bounds). pairs aliases Hb1:
    // CSR build completes before layer-1 gemm writes Hb1 (same stream).
    const bool twoBuf = ws_size >= off + hBytes;
    unsigned short* Hb1 = twoBuf ? (unsigned short*)(base + off)
                                 : (unsigned short*)d_in[0];
    int* pairs = (int*)Hb1;
    unsigned short* hb[2] = { Hb0, Hb1 };

    // ---- setup: memset bucketCnt; merged cast_x | cast_W | histogram ----
    hipMemsetAsync(bucketCnt, 0, 256 * sizeof(int), stream);
    const int n4 = N * D / 4;
    const int CB = (n4 + 255) / 256;
    setup_all<<<CB + 256 + NCHUNK, 256, 0, stream>>>((const float4*)x, (ushort4*)Hb0,
                                                     n4, CB, Ws, Wt, ec, E, bucketCnt);

    // ---- binned CSR build (once; reused by all 4 layers) ----
    bucket_scan<<<1, 256, 0, stream>>>(bucketCnt, bucketBase, globCursor);
    scatter_pairs<<<NCHUNK, 256, 0, stream>>>(er, ec, E, globCursor, pairs);
    fill_csr<<<NBUCK, 256, 0, stream>>>(pairs, bucketBase, bucketCnt, N, E, NBUCK,
                                        rowptr, dinv, srcs);
    // ---- pre-scale x-cast by dinv (S = dinv*x) ----
    const int nq = N * 16;                       // uint4 per row = 16
    scale_x<<<(nq + 255) / 256, 256, 0, stream>>>((uint4*)Hb0, dinv, nq);

    // ---- 4 fused layers: aggregate -> LDS A-tile -> MFMA (-> head dot) ----
    for (int i = 0; i < 4; ++i) {
        const unsigned short* Hc = hb[i & 1];
        unsigned short* Hn = hb[(i + 1) & 1];
        layer_fused<<<Npad / 64, 256, 0, stream>>>(rowptr, srcs, dinv, Hc,
                                                   Wt + (size_t)i * D * D,
                                                   bs + (size_t)i * D, Hn, dots, Wl,
                                                   N, (i == 3) ? 1 : 0);
    }

    // ---- mean pool (+bl) over fused per-node dots ----
    pool_graphs<<<NGRAPH, 256, 0, stream>>>(dots, batch, N, bl, (float*)d_out);
}

// Round 8
// 511.226 us; speedup vs baseline: 1.0186x; 1.0186x over previous
//
#include <hip/hip_runtime.h>

// ---------------------------------------------------------------------------
// GCN forward, reassociated: per layer h = relu( (A_hat h) W + b ).
// R20: PADDED CSR -> maskless straight-line gather pipeline.
// R19 post-mortem: conditional prefetch (if b+1<nb) gets flattened by the
// compiler (VGPR 68 vs audited 120) -> no pipelining, 2 rounds running.
// Fix: pad every row's source list to a multiple of 8 IN THE CSR; pad
// entries index row N, which is zero in both H buffers -> pad gathers add
// exactly 0 (and hit L1: same row every time). Inner loop is pure straight
// line: no masks, no tail, no branches; depth-2 h prefetch + srcs prefetch
// are unconditional (per-bucket slack filled with N makes overreads safe).
// Row descriptors (rowbeg/nbatch/dinv) prefetched one row ahead.
//  - fill_csr emits rowbeg[] (padded starts, +4096 slack per 512-row
//    bucket), nbatch[] (batch count), pad+slack filled with N.
//  - scatter_pairs CHUNK 4096->2048 (391 -> 782 blocks; was 1.5 blocks/CU).
//  - launch_bounds(256,2): no artificial VGPR pressure (R15/R19 lesson).
// Geometry (R18): 256-thread block = 4 independent waves, no barriers,
// wave-private 4.25KB LDS tile, 16 rows/wave. All layers pre-scaled
// (scale_x: S = dinv*h). Epilogue folds bias+relu+output-dinv; layer 4
// fuses the head dot. NOTE: harness delivers int32 edge_index/batch.
// ---------------------------------------------------------------------------

constexpr int D = 128;
constexpr int NGRAPH = 512;
constexpr int CHUNK = 2048;       // edges per scatter block
constexpr int BSH = 9;            // 512 nodes per bucket
constexpr int SLACK = 4096;       // per-bucket pad slack (512 rows x <=7) + guard
constexpr int OP = 136;           // out-tile pitch (ushorts): 272B, 16B-aligned rows

typedef __attribute__((ext_vector_type(8))) short bf16x8;
typedef __attribute__((ext_vector_type(4))) float f32x4;
typedef int i32x4u __attribute__((ext_vector_type(4), aligned(4)));

__device__ __forceinline__ float bf2f(unsigned short b) {
    return __uint_as_float(((unsigned int)b) << 16);
}
__device__ __forceinline__ unsigned short f2bf(float f) {   // round-to-nearest-even
    unsigned int u = __float_as_uint(f);
    u += 0x7FFFu + ((u >> 16) & 1u);
    return (unsigned short)(u >> 16);
}

// merged independent setup: [0,CB) cast x->bf16 | [CB,CB+256) cast W ->
// transposed bf16 Wt | [CB+256, ...) per-chunk bucket histogram.
__global__ __launch_bounds__(256) void setup_all(
        const float4* __restrict__ x4, ushort4* __restrict__ hb, int n4, int CB,
        const float* __restrict__ W, unsigned short* __restrict__ Wt,
        const int* __restrict__ ec, int E, int* __restrict__ bucketCnt) {
    __shared__ int h[256];
    const int t = threadIdx.x;
    const int b = blockIdx.x;
    if (b < CB) {
        int i = b * 256 + t;
        if (i < n4) {
            float4 v = x4[i];
            ushort4 o;
            o.x = f2bf(v.x); o.y = f2bf(v.y); o.z = f2bf(v.z); o.w = f2bf(v.w);
            hb[i] = o;
        }
    } else if (b < CB + 256) {
        int idx = (b - CB) * 256 + t;      // 4*128*128 = 65536 elems
        int i = idx >> 14;
        int rem = idx & 16383;
        int k = rem >> 7, c = rem & 127;
        Wt[(i << 14) + c * 128 + k] = f2bf(W[idx]);
    } else {
        h[t] = 0;
        __syncthreads();
        const int e0 = (b - CB - 256) * CHUNK;
        const int cnt = min(CHUNK, E - e0);
        for (int i = t; i < cnt; i += 256) atomicAdd(&h[ec[e0 + i] >> BSH], 1);
        __syncthreads();
        if (h[t]) atomicAdd(&bucketCnt[t], h[t]);
    }
}

// exclusive scan over 256 bucket counts -> bucketBase, globCursor
__global__ __launch_bounds__(256) void bucket_scan(const int* __restrict__ bucketCnt,
                                                   int* __restrict__ bucketBase,
                                                   int* __restrict__ globCursor) {
    __shared__ int s[256];
    const int t = threadIdx.x;
    int v = bucketCnt[t];
    s[t] = v; __syncthreads();
    for (int off = 1; off < 256; off <<= 1) {
        int x = (t >= off) ? s[t - off] : 0;
        __syncthreads();
        s[t] += x;
        __syncthreads();
    }
    int excl = s[t] - v;
    bucketBase[t] = excl;
    globCursor[t] = excl;
}

// scatter packed (r<<9 | c&511) into bucket-grouped array, LDS-staged
__global__ __launch_bounds__(256) void scatter_pairs(const int* __restrict__ er,
                                                     const int* __restrict__ ec, int E,
                                                     int* __restrict__ globCursor,
                                                     int* __restrict__ pairs) {
    __shared__ int h[256], lbase[256], cur[256], segd[256], s[256];
    __shared__ int stage[CHUNK];
    __shared__ unsigned char sb[CHUNK];
    const int t = threadIdx.x;
    const int e0 = blockIdx.x * CHUNK;
    const int cnt = min(CHUNK, E - e0);

    h[t] = 0;
    __syncthreads();
    for (int i = t; i < cnt; i += 256) atomicAdd(&h[ec[e0 + i] >> BSH], 1);
    __syncthreads();
    int v = h[t];
    s[t] = v; __syncthreads();
    for (int off = 1; off < 256; off <<= 1) {
        int x = (t >= off) ? s[t - off] : 0;
        __syncthreads();
        s[t] += x;
        __syncthreads();
    }
    lbase[t] = s[t] - v;
    cur[t] = s[t] - v;
    segd[t] = atomicAdd(&globCursor[t], v) - lbase[t];
    __syncthreads();
    for (int i = t; i < cnt; i += 256) {
        int c = ec[e0 + i];
        int b = c >> BSH;
        int p = atomicAdd(&cur[b], 1);
        stage[p] = (er[e0 + i] << BSH) | (c & 511);   // packed pair
        sb[p] = (unsigned char)b;
    }
    __syncthreads();
    for (int i = t; i < cnt; i += 256) {
        int b = sb[i];
        pairs[segd[b] + i] = stage[i];
    }
}

// one block per bucket. LDS hist+scan -> PADDED rowbeg/nbatch, dinv, srcs.
// Rows padded to a multiple of 8; pad entries = N (zero feature row).
// Per-bucket padded base = bucketBase[b] + b*SLACK; slack filled with N so
// the layer's unconditional srcs prefetch is always safe.
__global__ __launch_bounds__(256) void fill_csr(const int* __restrict__ pairs,
                                                const int* __restrict__ bucketBase,
                                                const int* __restrict__ bucketCnt,
                                                int N, int E, int NBUCK,
                                                int* __restrict__ rowbeg,
                                                int* __restrict__ nbatch,
                                                float* __restrict__ dinv,
                                                int* __restrict__ srcs) {
    __shared__ int hist[512], lofs[512], s[256];
    __shared__ int ptotS;
    const int t = threadIdx.x;
    const int b = blockIdx.x;
    const int c0 = b << BSH;
    const int base = bucketBase[b];
    const int cnt = bucketCnt[b];
    const int pbase = base + b * SLACK;
    const int* pp = pairs + base;

    hist[t] = 0; hist[t + 256] = 0;
    __syncthreads();
    for (int i = t; i < cnt; i += 256) atomicAdd(&hist[pp[i] & 511], 1);
    __syncthreads();
    const int a0 = hist[2 * t], a1 = hist[2 * t + 1];
    const int p0 = (a0 + 7) & ~7, p1 = (a1 + 7) & ~7;   // padded sizes
    s[t] = p0 + p1; __syncthreads();
    for (int off = 1; off < 256; off <<= 1) {
        int x = (t >= off) ? s[t - off] : 0;
        __syncthreads();
        s[t] += x;
        __syncthreads();
    }
    const int excl = s[t] - (p0 + p1);
    if (t == 255) ptotS = s[255];            // total padded size of bucket
    lofs[2 * t] = excl;
    lofs[2 * t + 1] = excl + p0;
    __syncthreads();
    const int nn = min(512, N - c0);
    for (int i = t; i < nn; i += 256) {
        rowbeg[c0 + i] = pbase + lofs[i];
        nbatch[c0 + i] = (hist[i] + 7) >> 3;
        dinv[c0 + i] = rsqrtf((float)hist[i] + 1.0f);
    }
    __syncthreads();
    // scatter real edges into padded slots (lofs becomes the fill cursor)
    for (int i = t; i < cnt; i += 256) {
        int pr = pp[i];
        int p = atomicAdd(&lofs[pr & 511], 1);
        srcs[pbase + p] = pr >> BSH;
    }
    // pad fill: rows' [start+deg, start+padded) <- N (disjoint from real slots)
    {
        int s0 = excl;
        for (int q = a0; q < p0; ++q) srcs[pbase + s0 + q] = N;
        int s1 = excl + p0;
        for (int q = a1; q < p1; ++q) srcs[pbase + s1 + q] = N;
    }
    // slack fill: [paddedTotal, cnt+SLACK) <- N (prefetch guard region)
    const int ptot = ptotS;
    for (int q = ptot + t; q < cnt + SLACK; q += 256) srcs[pbase + q] = N;
}

// scale the bf16 x-cast by dinv in place (S = dinv * x):
// one uint4 (8 bf16) per thread, 16 uint4 per row.
__global__ __launch_bounds__(256) void scale_x(uint4* __restrict__ Hb0,
                                               const float* __restrict__ dinv,
                                               int nq) {                // nq = N*16
    int i = blockIdx.x * 256 + threadIdx.x;
    if (i >= nq) return;
    float dv = dinv[i >> 4];
    uint4 v = Hb0[i];
    unsigned int* p = (unsigned int*)&v;
#pragma unroll
    for (int k = 0; k < 4; ++k) {
        unsigned int d = p[k];
        unsigned short lo = f2bf(bf2f((unsigned short)(d & 0xFFFFu)) * dv);
        unsigned short hi = f2bf(bf2f((unsigned short)(d >> 16)) * dv);
        p[k] = ((unsigned int)hi << 16) | lo;
    }
    Hb0[i] = v;
}

// ---------------------------------------------------------------------------
// Fused layer: 256-thread block = 4 independent waves (no barriers), each
// owning 16 rows + a private 4.25 KB LDS tile.
// Phase A: group `quad` (16 lanes) aggregates its 4 rows sequentially; lane
//   owns one 16B chunk of the 256B row. MASKLESS padded batches of 8:
//   pad sources = row N (all-zero) -> contribute 0, always L1-hot.
//   Depth-2 pipeline, all loads unconditional (slack-guarded):
//     gather h(b+1) from sB; reload sB at b+2; consume h(b); h = hn.
//   Row descriptors (rowbeg/nbatch/dinv) prefetched one row ahead.
//   Inputs pre-scaled S = dinv*h. P = dinv[row]*(sum S + S[row]) -> bf16
//   into xor-swizzled A-tile.
// Phase B: 16x16 MFMA; A-frags from LDS (conflict-free ds_read_b128),
//   W-frags from global (L2-hot). Epilogue folds bias+relu+output-dinv;
//   LDS tile reused as out tile (pitch OP) -> coalesced 16B stores.
//   Layer 4 (writeDots): head dot fused, no Hn write.
// C/D: col=lane&15, row=(lane>>4)*4+reg (verified mapping).
// ---------------------------------------------------------------------------
__global__ __launch_bounds__(256, 2) void layer_fused(
        const int* __restrict__ rowbeg, const int* __restrict__ nbatch,
        const int* __restrict__ srcs,
        const float* __restrict__ dinv, const unsigned short* __restrict__ H,
        const unsigned short* __restrict__ Wt, const float* __restrict__ bias,
        unsigned short* __restrict__ Hn, float* __restrict__ dots,
        const float* __restrict__ Wl, int N, int writeDots) {
    __shared__ __align__(16) unsigned short u[4][16 * OP];   // 17 KB, wave-private
    const int wave = threadIdx.x >> 6;
    const int lane = threadIdx.x & 63;
    const int row16 = lane & 15;
    const int quad = lane >> 4;
    const int r0 = blockIdx.x * 64 + wave * 16;
    unsigned short* U = u[wave];
    const bf16x8* H8 = (const bf16x8*)H;     // 16 chunks (16B) per row
    const int gl = row16;                    // chunk index this lane owns

    // ---- phase A: aggregate 16 rows (4 sequential per 16-lane group) ----
    // prefetch row 0 descriptors
    int rowP = r0 + quad * 4;
    int jrN = 0, nbN = 0; float snN = 0.f;
    if (rowP < N) { jrN = rowbeg[rowP]; nbN = nbatch[rowP]; snN = dinv[rowP]; }
#pragma unroll 1
    for (int sstep = 0; sstep < 4; ++sstep) {
        const int rt = quad * 4 + sstep;     // local row 0..15
        const int row = r0 + rt;
        const int jr = jrN, nb = nbN;
        const float sn = snN;
        // prefetch next row's descriptors (hidden under this row's gathers)
        if (sstep < 3) {
            const int rn = row + 1;
            if (rn < N) { jrN = rowbeg[rn]; nbN = nbatch[rn]; snN = dinv[rn]; }
            else { jrN = 0; nbN = 0; snN = 0.f; }
        }
        float acc[8] = {0.f, 0.f, 0.f, 0.f, 0.f, 0.f, 0.f, 0.f};
        if (row < N) {
            // self-loop term (pre-scaled)
            bf16x8 hv = H8[(size_t)row * 16 + gl];
#pragma unroll
            for (int k = 0; k < 8; ++k) acc[k] = bf2f((unsigned short)hv[k]);
            if (nb > 0) {
                // indices batch 0
                i32x4u sB0 = *(const i32x4u*)(srcs + jr);
                i32x4u sB1 = *(const i32x4u*)(srcs + jr + 4);
                bf16x8 h[8], hn[8];
#pragma unroll
                for (int t = 0; t < 8; ++t) {       // gather batch 0
                    int idx = (t < 4) ? sB0[t] : sB1[t - 4];
                    h[t] = H8[(size_t)idx * 16 + gl];
                }
                // indices batch 1 (unconditional; slack-guarded)
                sB0 = *(const i32x4u*)(srcs + jr + 8);
                sB1 = *(const i32x4u*)(srcs + jr + 12);
#pragma unroll 1
                for (int b = 0; b < nb - 1; ++b) {
#pragma unroll
                    for (int t = 0; t < 8; ++t) {   // gather batch b+1
                        int idx = (t < 4) ? sB0[t] : sB1[t - 4];
                        hn[t] = H8[(size_t)idx * 16 + gl];
                    }
                    // indices batch b+2 (unconditional; <=16 ints past row end)
                    sB0 = *(const i32x4u*)(srcs + jr + (b + 2) * 8);
                    sB1 = *(const i32x4u*)(srcs + jr + (b + 2) * 8 + 4);
                    // consume batch b (maskless: pads add H[N] = 0)
#pragma unroll
                    for (int t = 0; t < 8; ++t)
#pragma unroll
                        for (int k = 0; k < 8; ++k)
                            acc[k] += bf2f((unsigned short)h[t][k]);
#pragma unroll
                    for (int t = 0; t < 8; ++t) h[t] = hn[t];
                }
                // consume last batch
#pragma unroll
                for (int t = 0; t < 8; ++t)
#pragma unroll
                    for (int k = 0; k < 8; ++k)
                        acc[k] += bf2f((unsigned short)h[t][k]);
            }
        }
        // P row (bf16) -> swizzled A-tile; rows >= N become zeros (sn=0)
        bf16x8 o;
#pragma unroll
        for (int k = 0; k < 8; ++k) o[k] = (short)f2bf(sn * acc[k]);
        *(bf16x8*)(U + rt * 128 + ((gl ^ rt) << 3)) = o;
    }
    // no barrier: wave-private tile; lgkmcnt orders write->read within wave

    // ---- phase B: A fragments, all 4 K-chunks ----
    bf16x8 a0[4];
#pragma unroll
    for (int kc = 0; kc < 4; ++kc) {
        const int ph = (kc * 4 + quad) ^ row16;
        a0[kc] = *(const bf16x8*)(U + row16 * 128 + ph * 8);
    }
    // U is now reused as the out tile (pitch OP); same-wave aliasing ordered

    // dinv of output rows (pre-scale stored features); not needed for dots
    float dv[4];
    if (!writeDots) {
#pragma unroll
        for (int i = 0; i < 4; ++i) {
            int ra = r0 + quad * 4 + i;
            dv[i] = (ra < N) ? dinv[ra] : 0.f;
        }
    }

    float rd[4] = {0.f, 0.f, 0.f, 0.f};
#pragma unroll
    for (int ct = 0; ct < 8; ++ct) {
        const int col = ct * 16 + row16;
        const bf16x8* wc = (const bf16x8*)(Wt + (size_t)col * 128);
        f32x4 acc0 = {0.f, 0.f, 0.f, 0.f};
#pragma unroll
        for (int kc = 0; kc < 4; ++kc) {
            const bf16x8 wf = wc[kc * 4 + quad];
            acc0 = __builtin_amdgcn_mfma_f32_16x16x32_bf16(a0[kc], wf, acc0, 0, 0, 0);
        }
        const float bv = bias[col];
        if (writeDots) {
            const float wl = Wl[col];
#pragma unroll
            for (int i = 0; i < 4; ++i) rd[i] += fmaxf(acc0[i] + bv, 0.f) * wl;
        } else {
#pragma unroll
            for (int i = 0; i < 4; ++i)
                U[(quad * 4 + i) * OP + col] = f2bf(dv[i] * fmaxf(acc0[i] + bv, 0.f));
        }
    }

    if (writeDots) {
#pragma unroll
        for (int m = 1; m < 16; m <<= 1)
#pragma unroll
            for (int i = 0; i < 4; ++i) rd[i] += __shfl_xor(rd[i], m, 64);
        if (row16 == 0) {
#pragma unroll
            for (int i = 0; i < 4; ++i) dots[r0 + quad * 4 + i] = rd[i];
        }
    } else {
        // coalesced readback + store: 256 16B chunks per wave tile, 4/lane
#pragma unroll
        for (int i = 0; i < 4; ++i) {
            int idx = i * 64 + lane;
            int row = idx >> 4, c8 = idx & 15;
            bf16x8 v = *(const bf16x8*)(U + row * OP + c8 * 8);
            *(bf16x8*)(Hn + (size_t)(r0 + row) * 128 + c8 * 8) = v;
        }
    }
}

// one block per graph: binary-search node range in sorted batch, mean, +bl
__global__ __launch_bounds__(256) void pool_graphs(const float* __restrict__ dots,
                                                   const int* __restrict__ batch, int N,
                                                   const float* __restrict__ bl,
                                                   float* __restrict__ out) {
    __shared__ int bounds[2];
    __shared__ float red[4];
    const int g = blockIdx.x;
    const int t = threadIdx.x;
    if (t < 2) {
        int key = g + t;             // lower_bound(batch, key)
        int lo = 0, hi = N;
        while (lo < hi) {
            int mid = (lo + hi) >> 1;
            if (batch[mid] < key) lo = mid + 1; else hi = mid;
        }
        bounds[t] = lo;
    }
    __syncthreads();
    const int lo = bounds[0], hi = bounds[1];
    float s = 0.f;
    for (int i = lo + t; i < hi; i += 256) s += dots[i];
#pragma unroll
    for (int off = 32; off > 0; off >>= 1) s += __shfl_down(s, off, 64);
    if ((t & 63) == 0) red[t >> 6] = s;
    __syncthreads();
    if (t == 0) {
        float tot = red[0] + red[1] + red[2] + red[3];
        int cnt = hi - lo;
        out[g] = tot / (float)(cnt > 0 ? cnt : 1) + bl[0];
    }
}

extern "C" void kernel_launch(void* const* d_in, const int* in_sizes, int n_in,
                              void* d_out, int out_size, void* d_ws, size_t ws_size,
                              hipStream_t stream) {
    const float* x     = (const float*)d_in[0];
    const int*   eidx  = (const int*)d_in[1];    // int32 (harness converts int64)
    const int*   batch = (const int*)d_in[2];
    const float* Ws    = (const float*)d_in[3];
    const float* bs    = (const float*)d_in[4];
    const float* Wl    = (const float*)d_in[5];
    const float* bl    = (const float*)d_in[6];
    (void)n_in; (void)out_size;

    const int N = in_sizes[0] / D;
    const int E = in_sizes[1] / 2;
    const int* er = eidx;       // sources
    const int* ec = eidx + E;   // targets
    const int NBUCK = (N + 511) >> BSH;          // 512-node buckets (<= 256)
    const int NCHUNK = (E + CHUNK - 1) / CHUNK;

    // ---- workspace carve ----
    const int Npad = (N + 127) & ~127;
    const size_t hBytes = (size_t)Npad * D * sizeof(unsigned short); // 25.6 MB bf16
    auto al = [](size_t v) { return (v + 255) & ~(size_t)255; };
    char* base = (char*)d_ws;
    size_t off = 0;

    unsigned short* Hb0 = (unsigned short*)base; off = al(hBytes);
    int* bucketCnt  = (int*)(base + off);
    int* globCursor = bucketCnt + 256;
    off = al(off + 512 * sizeof(int));
    int*   bucketBase = (int*)(base + off);  off = al(off + 256 * sizeof(int));
    float* dinv   = (float*)(base + off);    off = al(off + (size_t)Npad * sizeof(float));
    float* dots   = (float*)(base + off);    off = al(off + (size_t)Npad * sizeof(float));
    int*   rowbeg = (int*)(base + off);      off = al(off + (size_t)Npad * sizeof(int));
    int*   nbatch = (int*)(base + off);      off = al(off + (size_t)Npad * sizeof(int));
    int*   srcs   = (int*)(base + off);
    off = al(off + ((size_t)E + (size_t)NBUCK * SLACK + 64) * sizeof(int));
    unsigned short* Wt = (unsigned short*)(base + off);   off = al(off + 4 * 128 * 128 * sizeof(unsigned short));

    // second bf16 buffer: in ws if it fits, else reuse x's 51.2 MB input buffer
    // (Npad*256B <= N*512B, so the alias stays in-bounds). pairs aliases Hb1:
    // CSR build completes before layer-1 gemm writes Hb1 (same stream).
    const bool twoBuf = ws_size >= off + hBytes;
    unsigned short* Hb1 = twoBuf ? (unsigned short*)(base + off)
                                 : (unsigned short*)d_in[0];
    int* pairs = (int*)Hb1;
    unsigned short* hb[2] = { Hb0, Hb1 };

    // ---- setup: zero bucketCnt + Hb0 pad rows (row N = zero pad target);
    //      merged cast_x | cast_W | histogram ----
    hipMemsetAsync(bucketCnt, 0, 256 * sizeof(int), stream);
    hipMemsetAsync(Hb0 + (size_t)N * D, 0, (size_t)(Npad - N) * D * sizeof(unsigned short), stream);
    const int n4 = N * D / 4;
    const int CB = (n4 + 255) / 256;
    setup_all<<<CB + 256 + NCHUNK, 256, 0, stream>>>((const float4*)x, (ushort4*)Hb0,
                                                     n4, CB, Ws, Wt, ec, E, bucketCnt);

    // ---- binned padded-CSR build (once; reused by all 4 layers) ----
    bucket_scan<<<1, 256, 0, stream>>>(bucketCnt, bucketBase, globCursor);
    scatter_pairs<<<NCHUNK, 256, 0, stream>>>(er, ec, E, globCursor, pairs);
    fill_csr<<<NBUCK, 256, 0, stream>>>(pairs, bucketBase, bucketCnt, N, E, NBUCK,
                                        rowbeg, nbatch, dinv, srcs);
    // ---- pre-scale x-cast by dinv (S = dinv*x) ----
    const int nq = N * 16;                       // uint4 per row = 16
    scale_x<<<(nq + 255) / 256, 256, 0, stream>>>((uint4*)Hb0, dinv, nq);

    // ---- 4 fused layers: aggregate -> LDS A-tile -> MFMA (-> head dot) ----
    for (int i = 0; i < 4; ++i) {
        const unsigned short* Hc = hb[i & 1];
        unsigned short* Hn = hb[(i + 1) & 1];
        layer_fused<<<Npad / 64, 256, 0, stream>>>(rowbeg, nbatch, srcs, dinv, Hc,
                                                   Wt + (size_t)i * D * D,
                                                   bs + (size_t)i * D, Hn, dots, Wl,
                                                   N, (i == 3) ? 1 : 0);
    }

    // ---- mean pool (+bl) over fused per-node dots ----
    pool_graphs<<<NGRAPH, 256, 0, stream>>>(dots, batch, N, bl, (float*)d_out);
}

// Round 9
// 489.950 us; speedup vs baseline: 1.0628x; 1.0434x over previous
//
#include <hip/hip_runtime.h>

// ---------------------------------------------------------------------------
// GCN forward, reassociated: per layer h = relu( (A_hat h) W + b ).
// R21: R17's best-measured layer structure + sched_barrier-forced pipeline.
// History: R17 (1-wave 16-row blocks, masked batches) = 78 us/layer, best.
// R18 (4-wave) 80.3; R19 (dual-row) 89; R20 (padded maskless) 87 — pads
// cost +18% gather instrs; compiler FLATTENED the depth-2 prefetch in
// R17/R19/R20 (VGPR 56/68/64 < the ~96 a live pipeline needs) by sinking
// the hn-gathers below the consume. Fix: __builtin_amdgcn_sched_barrier(0)
// between the hn-gather issue and the consume of h — a hard scheduling
// fence; loads issued before it cannot move after (guide §5.5 rule 18).
// Loop restructured: pipelined iterations consume FULL batches (maskless);
// one masked epilogue batch; srcs prefetch unconditional (+64 int slack).
// Kept from R18-R20: dedicated scale_x (not inside fill_csr), packed pairs
// (r<<9|c), CHUNK 2048. CSR unpadded (R20's padding regressed).
// All layers pre-scaled (S = dinv*h). Epilogue folds bias+relu+output-dinv;
// layer 4 fuses the head dot. NOTE: harness delivers int32 edge_index/batch.
// ---------------------------------------------------------------------------

constexpr int D = 128;
constexpr int NGRAPH = 512;
constexpr int CHUNK = 2048;       // edges per scatter block
constexpr int BSH = 9;            // 512 nodes per bucket
constexpr int OP = 136;           // out-tile pitch (ushorts): 272B, 16B-aligned rows

typedef __attribute__((ext_vector_type(8))) short bf16x8;
typedef __attribute__((ext_vector_type(4))) float f32x4;
typedef int i32x4u __attribute__((ext_vector_type(4), aligned(4)));

__device__ __forceinline__ float bf2f(unsigned short b) {
    return __uint_as_float(((unsigned int)b) << 16);
}
__device__ __forceinline__ unsigned short f2bf(float f) {   // round-to-nearest-even
    unsigned int u = __float_as_uint(f);
    u += 0x7FFFu + ((u >> 16) & 1u);
    return (unsigned short)(u >> 16);
}

// merged independent setup: [0,CB) cast x->bf16 | [CB,CB+256) cast W ->
// transposed bf16 Wt | [CB+256, ...) per-chunk bucket histogram.
__global__ __launch_bounds__(256) void setup_all(
        const float4* __restrict__ x4, ushort4* __restrict__ hb, int n4, int CB,
        const float* __restrict__ W, unsigned short* __restrict__ Wt,
        const int* __restrict__ ec, int E, int* __restrict__ bucketCnt) {
    __shared__ int h[256];
    const int t = threadIdx.x;
    const int b = blockIdx.x;
    if (b < CB) {
        int i = b * 256 + t;
        if (i < n4) {
            float4 v = x4[i];
            ushort4 o;
            o.x = f2bf(v.x); o.y = f2bf(v.y); o.z = f2bf(v.z); o.w = f2bf(v.w);
            hb[i] = o;
        }
    } else if (b < CB + 256) {
        int idx = (b - CB) * 256 + t;      // 4*128*128 = 65536 elems
        int i = idx >> 14;
        int rem = idx & 16383;
        int k = rem >> 7, c = rem & 127;
        Wt[(i << 14) + c * 128 + k] = f2bf(W[idx]);
    } else {
        h[t] = 0;
        __syncthreads();
        const int e0 = (b - CB - 256) * CHUNK;
        const int cnt = min(CHUNK, E - e0);
        for (int i = t; i < cnt; i += 256) atomicAdd(&h[ec[e0 + i] >> BSH], 1);
        __syncthreads();
        if (h[t]) atomicAdd(&bucketCnt[t], h[t]);
    }
}

// exclusive scan over 256 bucket counts -> bucketBase, globCursor
__global__ __launch_bounds__(256) void bucket_scan(const int* __restrict__ bucketCnt,
                                                   int* __restrict__ bucketBase,
                                                   int* __restrict__ globCursor) {
    __shared__ int s[256];
    const int t = threadIdx.x;
    int v = bucketCnt[t];
    s[t] = v; __syncthreads();
    for (int off = 1; off < 256; off <<= 1) {
        int x = (t >= off) ? s[t - off] : 0;
        __syncthreads();
        s[t] += x;
        __syncthreads();
    }
    int excl = s[t] - v;
    bucketBase[t] = excl;
    globCursor[t] = excl;
}

// scatter packed (r<<9 | c&511) into bucket-grouped array, LDS-staged
__global__ __launch_bounds__(256) void scatter_pairs(const int* __restrict__ er,
                                                     const int* __restrict__ ec, int E,
                                                     int* __restrict__ globCursor,
                                                     int* __restrict__ pairs) {
    __shared__ int h[256], lbase[256], cur[256], segd[256], s[256];
    __shared__ int stage[CHUNK];
    __shared__ unsigned char sb[CHUNK];
    const int t = threadIdx.x;
    const int e0 = blockIdx.x * CHUNK;
    const int cnt = min(CHUNK, E - e0);

    h[t] = 0;
    __syncthreads();
    for (int i = t; i < cnt; i += 256) atomicAdd(&h[ec[e0 + i] >> BSH], 1);
    __syncthreads();
    int v = h[t];
    s[t] = v; __syncthreads();
    for (int off = 1; off < 256; off <<= 1) {
        int x = (t >= off) ? s[t - off] : 0;
        __syncthreads();
        s[t] += x;
        __syncthreads();
    }
    lbase[t] = s[t] - v;
    cur[t] = s[t] - v;
    segd[t] = atomicAdd(&globCursor[t], v) - lbase[t];
    __syncthreads();
    for (int i = t; i < cnt; i += 256) {
        int c = ec[e0 + i];
        int b = c >> BSH;
        int p = atomicAdd(&cur[b], 1);
        stage[p] = (er[e0 + i] << BSH) | (c & 511);   // packed pair
        sb[p] = (unsigned char)b;
    }
    __syncthreads();
    for (int i = t; i < cnt; i += 256) {
        int b = sb[i];
        pairs[segd[b] + i] = stage[i];
    }
}

// one block per bucket. LDS hist+scan -> rowptr, dinv, slot fill. Unpadded.
__global__ __launch_bounds__(256) void fill_csr(const int* __restrict__ pairs,
                                                const int* __restrict__ bucketBase,
                                                const int* __restrict__ bucketCnt,
                                                int N, int E, int NBUCK,
                                                int* __restrict__ rowptr,
                                                float* __restrict__ dinv,
                                                int* __restrict__ srcs) {
    __shared__ int hist[512], lofs[512], s[256];
    const int t = threadIdx.x;
    const int b = blockIdx.x;
    const int c0 = b << BSH;
    const int base = bucketBase[b];
    const int cnt = bucketCnt[b];
    const int* pp = pairs + base;

    hist[t] = 0; hist[t + 256] = 0;
    __syncthreads();
    for (int i = t; i < cnt; i += 256) atomicAdd(&hist[pp[i] & 511], 1);
    __syncthreads();
    int a0 = hist[2 * t], a1 = hist[2 * t + 1];
    s[t] = a0 + a1; __syncthreads();
    for (int off = 1; off < 256; off <<= 1) {
        int x = (t >= off) ? s[t - off] : 0;
        __syncthreads();
        s[t] += x;
        __syncthreads();
    }
    int excl = s[t] - (a0 + a1);
    lofs[2 * t] = excl;
    lofs[2 * t + 1] = excl + a0;
    __syncthreads();
    const int nn = min(512, N - c0);
    for (int i = t; i < nn; i += 256) {
        rowptr[c0 + i] = base + lofs[i];
        dinv[c0 + i] = rsqrtf((float)hist[i] + 1.0f);
    }
    if (b == NBUCK - 1 && t == 0) rowptr[N] = E;
    __syncthreads();
    for (int i = t; i < cnt; i += 256) {
        int pr = pp[i];
        int p = atomicAdd(&lofs[pr & 511], 1);
        srcs[base + p] = pr >> BSH;
    }
}

// scale the bf16 x-cast by dinv in place (S = dinv * x):
// one uint4 (8 bf16) per thread, 16 uint4 per row.
__global__ __launch_bounds__(256) void scale_x(uint4* __restrict__ Hb0,
                                               const float* __restrict__ dinv,
                                               int nq) {                // nq = N*16
    int i = blockIdx.x * 256 + threadIdx.x;
    if (i >= nq) return;
    float dv = dinv[i >> 4];
    uint4 v = Hb0[i];
    unsigned int* p = (unsigned int*)&v;
#pragma unroll
    for (int k = 0; k < 4; ++k) {
        unsigned int d = p[k];
        unsigned short lo = f2bf(bf2f((unsigned short)(d & 0xFFFFu)) * dv);
        unsigned short hi = f2bf(bf2f((unsigned short)(d >> 16)) * dv);
        p[k] = ((unsigned int)hi << 16) | lo;
    }
    Hb0[i] = v;
}

// ---------------------------------------------------------------------------
// Fused layer: ONE WAVE per block, 16 target rows (R17 geometry — best
// measured). Phase A: 4 sixteen-lane groups; group `quad` owns 4 rows
// sequentially; lane owns one 16B chunk of the 256B row.
// Depth-2 pipeline, sched_barrier-pinned:
//   loop b in [0, nb-1): issue gathers for batch b+1 (masked only if it is
//   the final partial batch); issue srcs(b+2) unconditionally (slack-
//   guarded); sched_barrier(0) — loads may NOT sink below; consume batch b
//   MASKLESS (full by construction); h <- hn.
//   Epilogue: masked consume of the final batch.
// Inputs pre-scaled S = dinv*h. P = dinv[row]*(sum S + S[row]) -> bf16 into
// xor-swizzled A-tile. Phase B: 16x16 MFMA; A-frags from LDS (conflict-free
// ds_read_b128), W-frags from global (L2-hot); epilogue folds bias+relu+
// output-dinv; LDS reused as out tile (pitch OP) -> coalesced 16B stores.
// Layer 4 (writeDots): head dot fused, no Hn write.
// C/D: col=lane&15, row=(lane>>4)*4+reg (verified mapping).
// ---------------------------------------------------------------------------
__global__ __launch_bounds__(64, 4) void layer_fused(
        const int* __restrict__ rowptr, const int* __restrict__ srcs,
        const float* __restrict__ dinv, const unsigned short* __restrict__ H,
        const unsigned short* __restrict__ Wt, const float* __restrict__ bias,
        unsigned short* __restrict__ Hn, float* __restrict__ dots,
        const float* __restrict__ Wl, int N, int writeDots) {
    __shared__ __align__(16) unsigned short U[16 * OP];   // 4.25 KB
    const int lane = threadIdx.x;        // 0..63
    const int row16 = lane & 15;
    const int quad = lane >> 4;
    const int r0 = blockIdx.x * 16;
    const bf16x8* H8 = (const bf16x8*)H;     // 16 chunks (16B) per row
    const int gl = row16;                    // chunk index this lane owns

    // ---- phase A: aggregate 16 rows into swizzled LDS A-tile ----
#pragma unroll 1
    for (int sstep = 0; sstep < 4; ++sstep) {
        const int rt = quad * 4 + sstep;     // local row 0..15
        const int row = r0 + rt;
        float acc[8] = {0.f, 0.f, 0.f, 0.f, 0.f, 0.f, 0.f, 0.f};
        float sn = 0.f;
        if (row < N) {
            sn = dinv[row];
            const int j = rowptr[row];
            const int ne = rowptr[row + 1] - j;
            // self-loop term (pre-scaled)
            bf16x8 hv = H8[(size_t)row * 16 + gl];
#pragma unroll
            for (int k = 0; k < 8; ++k) acc[k] = bf2f((unsigned short)hv[k]);
            const int nb = (ne + 7) >> 3;     // 8-edge batches (last partial)
            if (nb > 0) {
                i32x4u s0 = *(const i32x4u*)(srcs + j);
                i32x4u s1 = *(const i32x4u*)(srcs + j + 4);
                bf16x8 h[8], hn[8];
#pragma unroll
                for (int t = 0; t < 8; ++t) {       // gather batch 0 (masked)
                    int idx = (t < 4) ? s0[t] : s1[t - 4];
                    int rr = (t < ne) ? idx : row;
                    h[t] = H8[(size_t)rr * 16 + gl];
                }
                // srcs(1), unconditional (slack-guarded read past row end ok)
                s0 = *(const i32x4u*)(srcs + j + 8);
                s1 = *(const i32x4u*)(srcs + j + 12);
#pragma unroll 1
                for (int b = 0; b + 1 < nb; ++b) {
                    const int remn = ne - (b + 1) * 8;
#pragma unroll
                    for (int t = 0; t < 8; ++t) {   // gather batch b+1
                        int idx = (t < 4) ? s0[t] : s1[t - 4];
                        int rr = (t < remn) ? idx : row;   // mask final partial
                        hn[t] = H8[(size_t)rr * 16 + gl];
                    }
                    // srcs(b+2), unconditional (slack-guarded)
                    s0 = *(const i32x4u*)(srcs + j + (b + 2) * 8);
                    s1 = *(const i32x4u*)(srcs + j + (b + 2) * 8 + 4);
                    // hard scheduling fence: gathers above may NOT sink below
                    __builtin_amdgcn_sched_barrier(0);
                    // consume batch b — full by construction, MASKLESS
#pragma unroll
                    for (int t = 0; t < 8; ++t)
#pragma unroll
                        for (int k = 0; k < 8; ++k)
                            acc[k] += bf2f((unsigned short)h[t][k]);
#pragma unroll
                    for (int t = 0; t < 8; ++t) h[t] = hn[t];
                }
                // epilogue: masked consume of final batch
                const int rem = ne - (nb - 1) * 8;
#pragma unroll
                for (int t = 0; t < 8; ++t) {
                    const float w = (t < rem) ? 1.f : 0.f;
#pragma unroll
                    for (int k = 0; k < 8; ++k)
                        acc[k] = fmaf(w, bf2f((unsigned short)h[t][k]), acc[k]);
                }
            }
        }
        // P row (bf16) -> swizzled A-tile; rows >= N become zeros (sn=0)
        bf16x8 o;
#pragma unroll
        for (int k = 0; k < 8; ++k) o[k] = (short)f2bf(sn * acc[k]);
        *(bf16x8*)(U + rt * 128 + ((gl ^ rt) << 3)) = o;
    }
    __syncthreads();   // 1-wave block: compiles to cnt drain, no stall

    // ---- phase B: A fragments, all 4 K-chunks ----
    bf16x8 a0[4];
#pragma unroll
    for (int kc = 0; kc < 4; ++kc) {
        const int ph = (kc * 4 + quad) ^ row16;
        a0[kc] = *(const bf16x8*)(U + row16 * 128 + ph * 8);
    }
    __syncthreads();   // U is now reused as the out tile (pitch OP)

    // dinv of output rows (pre-scale stored features); not needed for dots
    float dv[4];
    if (!writeDots) {
#pragma unroll
        for (int i = 0; i < 4; ++i) {
            int ra = r0 + quad * 4 + i;
            dv[i] = (ra < N) ? dinv[ra] : 0.f;
        }
    }

    float rd[4] = {0.f, 0.f, 0.f, 0.f};
#pragma unroll
    for (int ct = 0; ct < 8; ++ct) {
        const int col = ct * 16 + row16;
        const bf16x8* wc = (const bf16x8*)(Wt + (size_t)col * 128);
        f32x4 acc0 = {0.f, 0.f, 0.f, 0.f};
#pragma unroll
        for (int kc = 0; kc < 4; ++kc) {
            const bf16x8 wf = wc[kc * 4 + quad];
            acc0 = __builtin_amdgcn_mfma_f32_16x16x32_bf16(a0[kc], wf, acc0, 0, 0, 0);
        }
        const float bv = bias[col];
        if (writeDots) {
            const float wl = Wl[col];
#pragma unroll
            for (int i = 0; i < 4; ++i) rd[i] += fmaxf(acc0[i] + bv, 0.f) * wl;
        } else {
#pragma unroll
            for (int i = 0; i < 4; ++i)
                U[(quad * 4 + i) * OP + col] = f2bf(dv[i] * fmaxf(acc0[i] + bv, 0.f));
        }
    }

    if (writeDots) {
#pragma unroll
        for (int m = 1; m < 16; m <<= 1)
#pragma unroll
            for (int i = 0; i < 4; ++i) rd[i] += __shfl_xor(rd[i], m, 64);
        if (row16 == 0) {
#pragma unroll
            for (int i = 0; i < 4; ++i) dots[r0 + quad * 4 + i] = rd[i];
        }
    } else {
        __syncthreads();
        // coalesced readback + store: 256 16B chunks per tile, 4/lane
#pragma unroll
        for (int i = 0; i < 4; ++i) {
            int idx = i * 64 + lane;
            int row = idx >> 4, c8 = idx & 15;
            bf16x8 v = *(const bf16x8*)(U + row * OP + c8 * 8);
            *(bf16x8*)(Hn + (size_t)(r0 + row) * 128 + c8 * 8) = v;
        }
    }
}

// one block per graph: binary-search node range in sorted batch, mean, +bl
__global__ __launch_bounds__(256) void pool_graphs(const float* __restrict__ dots,
                                                   const int* __restrict__ batch, int N,
                                                   const float* __restrict__ bl,
                                                   float* __restrict__ out) {
    __shared__ int bounds[2];
    __shared__ float red[4];
    const int g = blockIdx.x;
    const int t = threadIdx.x;
    if (t < 2) {
        int key = g + t;             // lower_bound(batch, key)
        int lo = 0, hi = N;
        while (lo < hi) {
            int mid = (lo + hi) >> 1;
            if (batch[mid] < key) lo = mid + 1; else hi = mid;
        }
        bounds[t] = lo;
    }
    __syncthreads();
    const int lo = bounds[0], hi = bounds[1];
    float s = 0.f;
    for (int i = lo + t; i < hi; i += 256) s += dots[i];
#pragma unroll
    for (int off = 32; off > 0; off >>= 1) s += __shfl_down(s, off, 64);
    if ((t & 63) == 0) red[t >> 6] = s;
    __syncthreads();
    if (t == 0) {
        float tot = red[0] + red[1] + red[2] + red[3];
        int cnt = hi - lo;
        out[g] = tot / (float)(cnt > 0 ? cnt : 1) + bl[0];
    }
}

extern "C" void kernel_launch(void* const* d_in, const int* in_sizes, int n_in,
                              void* d_out, int out_size, void* d_ws, size_t ws_size,
                              hipStream_t stream) {
    const float* x     = (const float*)d_in[0];
    const int*   eidx  = (const int*)d_in[1];    // int32 (harness converts int64)
    const int*   batch = (const int*)d_in[2];
    const float* Ws    = (const float*)d_in[3];
    const float* bs    = (const float*)d_in[4];
    const float* Wl    = (const float*)d_in[5];
    const float* bl    = (const float*)d_in[6];
    (void)n_in; (void)out_size;

    const int N = in_sizes[0] / D;
    const int E = in_sizes[1] / 2;
    const int* er = eidx;       // sources
    const int* ec = eidx + E;   // targets
    const int NBUCK = (N + 511) >> BSH;          // 512-node buckets (<= 256)
    const int NCHUNK = (E + CHUNK - 1) / CHUNK;

    // ---- workspace carve ----
    const int Npad = (N + 127) & ~127;
    const size_t hBytes = (size_t)Npad * D * sizeof(unsigned short); // 25.6 MB bf16
    auto al = [](size_t v) { return (v + 255) & ~(size_t)255; };
    char* base = (char*)d_ws;
    size_t off = 0;

    unsigned short* Hb0 = (unsigned short*)base; off = al(hBytes);
    int* bucketCnt  = (int*)(base + off);
    int* globCursor = bucketCnt + 256;
    off = al(off + 512 * sizeof(int));
    int*   bucketBase = (int*)(base + off);  off = al(off + 256 * sizeof(int));
    float* dinv   = (float*)(base + off);    off = al(off + (size_t)Npad * sizeof(float));
    float* dots   = (float*)(base + off);    off = al(off + (size_t)Npad * sizeof(float));
    int*   rowptr = (int*)(base + off);      off = al(off + (size_t)(Npad + 64) * sizeof(int));
    int*   srcs   = (int*)(base + off);      off = al(off + ((size_t)E + 64) * sizeof(int));
    unsigned short* Wt = (unsigned short*)(base + off);   off = al(off + 4 * 128 * 128 * sizeof(unsigned short));

    // second bf16 buffer: in ws if it fits, else reuse x's 51.2 MB input buffer
    // (Npad*256B <= N*512B, so the alias stays in-bounds). pairs aliases Hb1:
    // CSR build completes before layer-1 gemm writes Hb1 (same stream).
    const bool twoBuf = ws_size >= off + hBytes;
    unsigned short* Hb1 = twoBuf ? (unsigned short*)(base + off)
                                 : (unsigned short*)d_in[0];
    int* pairs = (int*)Hb1;
    unsigned short* hb[2] = { Hb0, Hb1 };

    // ---- setup: memset bucketCnt; merged cast_x | cast_W | histogram ----
    hipMemsetAsync(bucketCnt, 0, 256 * sizeof(int), stream);
    const int n4 = N * D / 4;
    const int CB = (n4 + 255) / 256;
    setup_all<<<CB + 256 + NCHUNK, 256, 0, stream>>>((const float4*)x, (ushort4*)Hb0,
                                                     n4, CB, Ws, Wt, ec, E, bucketCnt);

    // ---- binned CSR build (once; reused by all 4 layers) ----
    bucket_scan<<<1, 256, 0, stream>>>(bucketCnt, bucketBase, globCursor);
    scatter_pairs<<<NCHUNK, 256, 0, stream>>>(er, ec, E, globCursor, pairs);
    fill_csr<<<NBUCK, 256, 0, stream>>>(pairs, bucketBase, bucketCnt, N, E, NBUCK,
                                        rowptr, dinv, srcs);
    // ---- pre-scale x-cast by dinv (S = dinv*x) ----
    const int nq = N * 16;                       // uint4 per row = 16
    scale_x<<<(nq + 255) / 256, 256, 0, stream>>>((uint4*)Hb0, dinv, nq);

    // ---- 4 fused layers: aggregate -> LDS A-tile -> MFMA (-> head dot) ----
    for (int i = 0; i < 4; ++i) {
        const unsigned short* Hc = hb[i & 1];
        unsigned short* Hn = hb[(i + 1) & 1];
        layer_fused<<<Npad / 16, 64, 0, stream>>>(rowptr, srcs, dinv, Hc,
                                                  Wt + (size_t)i * D * D,
                                                  bs + (size_t)i * D, Hn, dots, Wl,
                                                  N, (i == 3) ? 1 : 0);
    }

    // ---- mean pool (+bl) over fused per-node dots ----
    pool_graphs<<<NGRAPH, 256, 0, stream>>>(dots, batch, N, bl, (float*)d_out);
}

// Round 10
// 466.884 us; speedup vs baseline: 1.1153x; 1.0494x over previous
//
#include <hip/hip_runtime.h>

// ---------------------------------------------------------------------------
// GCN forward, reassociated: per layer h = relu( (A_hat h) W + b ).
// R22: 2-wave blocks per 16-row tile -> 2x total waves, 2 rows per group.
// Evidence (R12-R21): same FETCH (~195MB) at 2.5-2.9 TB/s for every fused
// variant (<=6256 waves), but 67.5us (3.3 TB/s) for R12's split pull with
// 50000 waves. Rate tracks resident wave count; per-wave ILP attempts
// (R17/R19/R20/R21 pipelining) were all flattened by the compiler (VGPR
// 52-68) or regressed. Fix: block = 128 threads (2 waves) per 16-row MFMA
// tile; phase A: 8 sixteen-lane groups x 2 rows each (serial chains 4->2);
// grid 6256 blocks = 12512 waves (48.8/CU available, 16-wg cap -> 32
// resident). Phase B split by column tiles: wave w does ct=4w..4w+3, both
// read the same LDS A-frags, disjoint out columns; head-dot layer does a
// small cross-wave LDS reduce. Inner gather loop = R17's proven masked
// batches (best measured, 78us at 1/2 the waves).
// Kept: dedicated scale_x, packed pairs, CHUNK 2048, unpadded CSR.
// All layers pre-scaled (S = dinv*h). Epilogue folds bias+relu+output-dinv;
// layer 4 fuses the head dot. NOTE: harness delivers int32 edge_index/batch.
// ---------------------------------------------------------------------------

constexpr int D = 128;
constexpr int NGRAPH = 512;
constexpr int CHUNK = 2048;       // edges per scatter block
constexpr int BSH = 9;            // 512 nodes per bucket
constexpr int OP = 136;           // out-tile pitch (ushorts): 272B, 16B-aligned rows

typedef __attribute__((ext_vector_type(8))) short bf16x8;
typedef __attribute__((ext_vector_type(4))) float f32x4;
typedef int i32x4u __attribute__((ext_vector_type(4), aligned(4)));

__device__ __forceinline__ float bf2f(unsigned short b) {
    return __uint_as_float(((unsigned int)b) << 16);
}
__device__ __forceinline__ unsigned short f2bf(float f) {   // round-to-nearest-even
    unsigned int u = __float_as_uint(f);
    u += 0x7FFFu + ((u >> 16) & 1u);
    return (unsigned short)(u >> 16);
}

// merged independent setup: [0,CB) cast x->bf16 | [CB,CB+256) cast W ->
// transposed bf16 Wt | [CB+256, ...) per-chunk bucket histogram.
__global__ __launch_bounds__(256) void setup_all(
        const float4* __restrict__ x4, ushort4* __restrict__ hb, int n4, int CB,
        const float* __restrict__ W, unsigned short* __restrict__ Wt,
        const int* __restrict__ ec, int E, int* __restrict__ bucketCnt) {
    __shared__ int h[256];
    const int t = threadIdx.x;
    const int b = blockIdx.x;
    if (b < CB) {
        int i = b * 256 + t;
        if (i < n4) {
            float4 v = x4[i];
            ushort4 o;
            o.x = f2bf(v.x); o.y = f2bf(v.y); o.z = f2bf(v.z); o.w = f2bf(v.w);
            hb[i] = o;
        }
    } else if (b < CB + 256) {
        int idx = (b - CB) * 256 + t;      // 4*128*128 = 65536 elems
        int i = idx >> 14;
        int rem = idx & 16383;
        int k = rem >> 7, c = rem & 127;
        Wt[(i << 14) + c * 128 + k] = f2bf(W[idx]);
    } else {
        h[t] = 0;
        __syncthreads();
        const int e0 = (b - CB - 256) * CHUNK;
        const int cnt = min(CHUNK, E - e0);
        for (int i = t; i < cnt; i += 256) atomicAdd(&h[ec[e0 + i] >> BSH], 1);
        __syncthreads();
        if (h[t]) atomicAdd(&bucketCnt[t], h[t]);
    }
}

// exclusive scan over 256 bucket counts -> bucketBase, globCursor
__global__ __launch_bounds__(256) void bucket_scan(const int* __restrict__ bucketCnt,
                                                   int* __restrict__ bucketBase,
                                                   int* __restrict__ globCursor) {
    __shared__ int s[256];
    const int t = threadIdx.x;
    int v = bucketCnt[t];
    s[t] = v; __syncthreads();
    for (int off = 1; off < 256; off <<= 1) {
        int x = (t >= off) ? s[t - off] : 0;
        __syncthreads();
        s[t] += x;
        __syncthreads();
    }
    int excl = s[t] - v;
    bucketBase[t] = excl;
    globCursor[t] = excl;
}

// scatter packed (r<<9 | c&511) into bucket-grouped array, LDS-staged
__global__ __launch_bounds__(256) void scatter_pairs(const int* __restrict__ er,
                                                     const int* __restrict__ ec, int E,
                                                     int* __restrict__ globCursor,
                                                     int* __restrict__ pairs) {
    __shared__ int h[256], lbase[256], cur[256], segd[256], s[256];
    __shared__ int stage[CHUNK];
    __shared__ unsigned char sb[CHUNK];
    const int t = threadIdx.x;
    const int e0 = blockIdx.x * CHUNK;
    const int cnt = min(CHUNK, E - e0);

    h[t] = 0;
    __syncthreads();
    for (int i = t; i < cnt; i += 256) atomicAdd(&h[ec[e0 + i] >> BSH], 1);
    __syncthreads();
    int v = h[t];
    s[t] = v; __syncthreads();
    for (int off = 1; off < 256; off <<= 1) {
        int x = (t >= off) ? s[t - off] : 0;
        __syncthreads();
        s[t] += x;
        __syncthreads();
    }
    lbase[t] = s[t] - v;
    cur[t] = s[t] - v;
    segd[t] = atomicAdd(&globCursor[t], v) - lbase[t];
    __syncthreads();
    for (int i = t; i < cnt; i += 256) {
        int c = ec[e0 + i];
        int b = c >> BSH;
        int p = atomicAdd(&cur[b], 1);
        stage[p] = (er[e0 + i] << BSH) | (c & 511);   // packed pair
        sb[p] = (unsigned char)b;
    }
    __syncthreads();
    for (int i = t; i < cnt; i += 256) {
        int b = sb[i];
        pairs[segd[b] + i] = stage[i];
    }
}

// one block per bucket. LDS hist+scan -> rowptr, dinv, slot fill. Unpadded.
__global__ __launch_bounds__(256) void fill_csr(const int* __restrict__ pairs,
                                                const int* __restrict__ bucketBase,
                                                const int* __restrict__ bucketCnt,
                                                int N, int E, int NBUCK,
                                                int* __restrict__ rowptr,
                                                float* __restrict__ dinv,
                                                int* __restrict__ srcs) {
    __shared__ int hist[512], lofs[512], s[256];
    const int t = threadIdx.x;
    const int b = blockIdx.x;
    const int c0 = b << BSH;
    const int base = bucketBase[b];
    const int cnt = bucketCnt[b];
    const int* pp = pairs + base;

    hist[t] = 0; hist[t + 256] = 0;
    __syncthreads();
    for (int i = t; i < cnt; i += 256) atomicAdd(&hist[pp[i] & 511], 1);
    __syncthreads();
    int a0 = hist[2 * t], a1 = hist[2 * t + 1];
    s[t] = a0 + a1; __syncthreads();
    for (int off = 1; off < 256; off <<= 1) {
        int x = (t >= off) ? s[t - off] : 0;
        __syncthreads();
        s[t] += x;
        __syncthreads();
    }
    int excl = s[t] - (a0 + a1);
    lofs[2 * t] = excl;
    lofs[2 * t + 1] = excl + a0;
    __syncthreads();
    const int nn = min(512, N - c0);
    for (int i = t; i < nn; i += 256) {
        rowptr[c0 + i] = base + lofs[i];
        dinv[c0 + i] = rsqrtf((float)hist[i] + 1.0f);
    }
    if (b == NBUCK - 1 && t == 0) rowptr[N] = E;
    __syncthreads();
    for (int i = t; i < cnt; i += 256) {
        int pr = pp[i];
        int p = atomicAdd(&lofs[pr & 511], 1);
        srcs[base + p] = pr >> BSH;
    }
}

// scale the bf16 x-cast by dinv in place (S = dinv * x):
// one uint4 (8 bf16) per thread, 16 uint4 per row.
__global__ __launch_bounds__(256) void scale_x(uint4* __restrict__ Hb0,
                                               const float* __restrict__ dinv,
                                               int nq) {                // nq = N*16
    int i = blockIdx.x * 256 + threadIdx.x;
    if (i >= nq) return;
    float dv = dinv[i >> 4];
    uint4 v = Hb0[i];
    unsigned int* p = (unsigned int*)&v;
#pragma unroll
    for (int k = 0; k < 4; ++k) {
        unsigned int d = p[k];
        unsigned short lo = f2bf(bf2f((unsigned short)(d & 0xFFFFu)) * dv);
        unsigned short hi = f2bf(bf2f((unsigned short)(d >> 16)) * dv);
        p[k] = ((unsigned int)hi << 16) | lo;
    }
    Hb0[i] = v;
}

// ---------------------------------------------------------------------------
// Fused layer: 128-thread block (2 waves) per 16-row tile.
// Phase A: 8 sixteen-lane groups (grp = wave*4+quad); group aggregates rows
//   grp*2, grp*2+1 sequentially; lane owns one 16B chunk of the 256B row.
//   R17's masked 8-edge batch loop (best measured). Inputs pre-scaled
//   S = dinv*h. P = dinv[row]*(sum S + S[row]) -> bf16, xor-swizzled A-tile.
// Phase B (split): barrier; both waves load the same A-frags; barrier;
//   wave w computes column-tiles ct = 4w..4w+3 (disjoint out columns).
//   Epilogue folds bias+relu+output-dinv into the shared out tile
//   (pitch OP); barrier; coalesced 16B readback+stores (2 chunks/thread).
//   Layer 4 (writeDots): intra-wave shfl reduce + cross-wave LDS reduce.
// C/D: col=lane&15, row=(lane>>4)*4+reg (verified mapping).
// ---------------------------------------------------------------------------
__global__ __launch_bounds__(128, 4) void layer_fused(
        const int* __restrict__ rowptr, const int* __restrict__ srcs,
        const float* __restrict__ dinv, const unsigned short* __restrict__ H,
        const unsigned short* __restrict__ Wt, const float* __restrict__ bias,
        unsigned short* __restrict__ Hn, float* __restrict__ dots,
        const float* __restrict__ Wl, int N, int writeDots) {
    __shared__ __align__(16) unsigned short U[16 * OP];   // 4.25 KB
    const int tid = threadIdx.x;         // 0..127
    const int wave = tid >> 6;           // 0..1
    const int lane = tid & 63;
    const int row16 = lane & 15;
    const int quad = lane >> 4;          // 0..3
    const int grp = wave * 4 + quad;     // 0..7
    const int r0 = blockIdx.x * 16;
    const bf16x8* H8 = (const bf16x8*)H;     // 16 chunks (16B) per row
    const int gl = row16;                    // chunk index this lane owns

    // ---- phase A: each group aggregates 2 rows into swizzled A-tile ----
#pragma unroll 1
    for (int ss = 0; ss < 2; ++ss) {
        const int rt = grp * 2 + ss;     // local row 0..15
        const int row = r0 + rt;
        float acc[8] = {0.f, 0.f, 0.f, 0.f, 0.f, 0.f, 0.f, 0.f};
        float sn = 0.f;
        if (row < N) {
            sn = dinv[row];
            int j = rowptr[row];
            const int end = rowptr[row + 1];
            // self-loop term (pre-scaled)
            bf16x8 hv = H8[(size_t)row * 16 + gl];
#pragma unroll
            for (int k = 0; k < 8; ++k) acc[k] = bf2f((unsigned short)hv[k]);
            const int ne = end - j;
            const int nb = (ne + 7) >> 3;     // masked 8-edge batches
            if (nb > 0) {
                i32x4u sA0, sA1, sB0, sB1;
                {   // srcs(0); srcs(1) issued BEFORE h(0)
                    const i32x4u* sp = (const i32x4u*)(srcs + j);
                    sA0 = sp[0]; sA1 = sp[1];
                }
                if (nb > 1) {
                    const i32x4u* sp = (const i32x4u*)(srcs + j + 8);
                    sB0 = sp[0]; sB1 = sp[1];
                }
                bf16x8 hc[8], hn[8];
#pragma unroll
                for (int t = 0; t < 8; ++t) {       // issue h(0)
                    int idx = (t < 4) ? sA0[t] : sA1[t - 4];
                    int rr = (t < ne) ? idx : row;
                    hc[t] = H8[(size_t)rr * 16 + gl];
                }
#pragma unroll 1
                for (int b = 0; b < nb; ++b) {
                    if (b + 1 < nb) {
                        const int remn = ne - (b + 1) * 8;
                        int rn[8];
#pragma unroll
                        for (int t = 0; t < 8; ++t) {   // waits srcs(b+1) only
                            int idx = (t < 4) ? sB0[t] : sB1[t - 4];
                            rn[t] = (t < remn) ? idx : row;
                        }
                        if (b + 2 < nb) {               // srcs(b+2) BEFORE h(b+1)
                            const i32x4u* sp = (const i32x4u*)(srcs + j + (b + 2) * 8);
                            sB0 = sp[0]; sB1 = sp[1];
                        }
#pragma unroll
                        for (int t = 0; t < 8; ++t)     // issue h(b+1)
                            hn[t] = H8[(size_t)rn[t] * 16 + gl];
                    }
                    // consume h(b); weight from remaining count
                    const int rem = ne - b * 8;
#pragma unroll
                    for (int t = 0; t < 8; ++t) {
                        const float w = (t < rem) ? 1.f : 0.f;
#pragma unroll
                        for (int k = 0; k < 8; ++k)
                            acc[k] = fmaf(w, bf2f((unsigned short)hc[t][k]), acc[k]);
                    }
#pragma unroll
                    for (int t = 0; t < 8; ++t) hc[t] = hn[t];
                }
            }
        }
        // P row (bf16) -> swizzled A-tile; rows >= N become zeros (sn=0)
        bf16x8 o;
#pragma unroll
        for (int k = 0; k < 8; ++k) o[k] = (short)f2bf(sn * acc[k]);
        *(bf16x8*)(U + rt * 128 + ((gl ^ rt) << 3)) = o;
    }
    __syncthreads();

    // ---- phase B: both waves load the same A fragments ----
    bf16x8 a0[4];
#pragma unroll
    for (int kc = 0; kc < 4; ++kc) {
        const int ph = (kc * 4 + quad) ^ row16;
        a0[kc] = *(const bf16x8*)(U + row16 * 128 + ph * 8);
    }
    __syncthreads();   // U is now reused as the out tile (pitch OP)

    // dinv of output rows (pre-scale stored features); not needed for dots
    float dv[4];
    if (!writeDots) {
#pragma unroll
        for (int i = 0; i < 4; ++i) {
            int ra = r0 + quad * 4 + i;
            dv[i] = (ra < N) ? dinv[ra] : 0.f;
        }
    }

    // wave w handles column-tiles ct = 4w .. 4w+3
    float rd[4] = {0.f, 0.f, 0.f, 0.f};
#pragma unroll
    for (int c = 0; c < 4; ++c) {
        const int ct = wave * 4 + c;
        const int col = ct * 16 + row16;
        const bf16x8* wc = (const bf16x8*)(Wt + (size_t)col * 128);
        f32x4 acc0 = {0.f, 0.f, 0.f, 0.f};
#pragma unroll
        for (int kc = 0; kc < 4; ++kc) {
            const bf16x8 wf = wc[kc * 4 + quad];
            acc0 = __builtin_amdgcn_mfma_f32_16x16x32_bf16(a0[kc], wf, acc0, 0, 0, 0);
        }
        const float bv = bias[col];
        if (writeDots) {
            const float wl = Wl[col];
#pragma unroll
            for (int i = 0; i < 4; ++i) rd[i] += fmaxf(acc0[i] + bv, 0.f) * wl;
        } else {
#pragma unroll
            for (int i = 0; i < 4; ++i)
                U[(quad * 4 + i) * OP + col] = f2bf(dv[i] * fmaxf(acc0[i] + bv, 0.f));
        }
    }

    if (writeDots) {
        // intra-wave: sum over the 16 cols of each ct (lanes of same quad)
#pragma unroll
        for (int m = 1; m < 16; m <<= 1)
#pragma unroll
            for (int i = 0; i < 4; ++i) rd[i] += __shfl_xor(rd[i], m, 64);
        // cross-wave: partials via LDS (U reused as float scratch)
        float* R = (float*)U;
        if (row16 == 0) {
#pragma unroll
            for (int i = 0; i < 4; ++i) R[wave * 16 + quad * 4 + i] = rd[i];
        }
        __syncthreads();
        if (tid < 16) dots[r0 + tid] = R[tid] + R[16 + tid];
    } else {
        __syncthreads();
        // coalesced readback + store: 256 16B chunks, 2 per thread
#pragma unroll
        for (int i = 0; i < 2; ++i) {
            int idx = i * 128 + tid;
            int row = idx >> 4, c8 = idx & 15;
            bf16x8 v = *(const bf16x8*)(U + row * OP + c8 * 8);
            *(bf16x8*)(Hn + (size_t)(r0 + row) * 128 + c8 * 8) = v;
        }
    }
}

// one block per graph: binary-search node range in sorted batch, mean, +bl
__global__ __launch_bounds__(256) void pool_graphs(const float* __restrict__ dots,
                                                   const int* __restrict__ batch, int N,
                                                   const float* __restrict__ bl,
                                                   float* __restrict__ out) {
    __shared__ int bounds[2];
    __shared__ float red[4];
    const int g = blockIdx.x;
    const int t = threadIdx.x;
    if (t < 2) {
        int key = g + t;             // lower_bound(batch, key)
        int lo = 0, hi = N;
        while (lo < hi) {
            int mid = (lo + hi) >> 1;
            if (batch[mid] < key) lo = mid + 1; else hi = mid;
        }
        bounds[t] = lo;
    }
    __syncthreads();
    const int lo = bounds[0], hi = bounds[1];
    float s = 0.f;
    for (int i = lo + t; i < hi; i += 256) s += dots[i];
#pragma unroll
    for (int off = 32; off > 0; off >>= 1) s += __shfl_down(s, off, 64);
    if ((t & 63) == 0) red[t >> 6] = s;
    __syncthreads();
    if (t == 0) {
        float tot = red[0] + red[1] + red[2] + red[3];
        int cnt = hi - lo;
        out[g] = tot / (float)(cnt > 0 ? cnt : 1) + bl[0];
    }
}

extern "C" void kernel_launch(void* const* d_in, const int* in_sizes, int n_in,
                              void* d_out, int out_size, void* d_ws, size_t ws_size,
                              hipStream_t stream) {
    const float* x     = (const float*)d_in[0];
    const int*   eidx  = (const int*)d_in[1];    // int32 (harness converts int64)
    const int*   batch = (const int*)d_in[2];
    const float* Ws    = (const float*)d_in[3];
    const float* bs    = (const float*)d_in[4];
    const float* Wl    = (const float*)d_in[5];
    const float* bl    = (const float*)d_in[6];
    (void)n_in; (void)out_size;

    const int N = in_sizes[0] / D;
    const int E = in_sizes[1] / 2;
    const int* er = eidx;       // sources
    const int* ec = eidx + E;   // targets
    const int NBUCK = (N + 511) >> BSH;          // 512-node buckets (<= 256)
    const int NCHUNK = (E + CHUNK - 1) / CHUNK;

    // ---- workspace carve ----
    const int Npad = (N + 127) & ~127;
    const size_t hBytes = (size_t)Npad * D * sizeof(unsigned short); // 25.6 MB bf16
    auto al = [](size_t v) { return (v + 255) & ~(size_t)255; };
    char* base = (char*)d_ws;
    size_t off = 0;

    unsigned short* Hb0 = (unsigned short*)base; off = al(hBytes);
    int* bucketCnt  = (int*)(base + off);
    int* globCursor = bucketCnt + 256;
    off = al(off + 512 * sizeof(int));
    int*   bucketBase = (int*)(base + off);  off = al(off + 256 * sizeof(int));
    float* dinv   = (float*)(base + off);    off = al(off + (size_t)Npad * sizeof(float));
    float* dots   = (float*)(base + off);    off = al(off + (size_t)Npad * sizeof(float));
    int*   rowptr = (int*)(base + off);      off = al(off + (size_t)(Npad + 64) * sizeof(int));
    int*   srcs   = (int*)(base + off);      off = al(off + ((size_t)E + 64) * sizeof(int));
    unsigned short* Wt = (unsigned short*)(base + off);   off = al(off + 4 * 128 * 128 * sizeof(unsigned short));

    // second bf16 buffer: in ws if it fits, else reuse x's 51.2 MB input buffer
    // (Npad*256B <= N*512B, so the alias stays in-bounds). pairs aliases Hb1:
    // CSR build completes before layer-1 gemm writes Hb1 (same stream).
    const bool twoBuf = ws_size >= off + hBytes;
    unsigned short* Hb1 = twoBuf ? (unsigned short*)(base + off)
                                 : (unsigned short*)d_in[0];
    int* pairs = (int*)Hb1;
    unsigned short* hb[2] = { Hb0, Hb1 };

    // ---- setup: memset bucketCnt; merged cast_x | cast_W | histogram ----
    hipMemsetAsync(bucketCnt, 0, 256 * sizeof(int), stream);
    const int n4 = N * D / 4;
    const int CB = (n4 + 255) / 256;
    setup_all<<<CB + 256 + NCHUNK, 256, 0, stream>>>((const float4*)x, (ushort4*)Hb0,
                                                     n4, CB, Ws, Wt, ec, E, bucketCnt);

    // ---- binned CSR build (once; reused by all 4 layers) ----
    bucket_scan<<<1, 256, 0, stream>>>(bucketCnt, bucketBase, globCursor);
    scatter_pairs<<<NCHUNK, 256, 0, stream>>>(er, ec, E, globCursor, pairs);
    fill_csr<<<NBUCK, 256, 0, stream>>>(pairs, bucketBase, bucketCnt, N, E, NBUCK,
                                        rowptr, dinv, srcs);
    // ---- pre-scale x-cast by dinv (S = dinv*x) ----
    const int nq = N * 16;                       // uint4 per row = 16
    scale_x<<<(nq + 255) / 256, 256, 0, stream>>>((uint4*)Hb0, dinv, nq);

    // ---- 4 fused layers: aggregate -> LDS A-tile -> MFMA (-> head dot) ----
    for (int i = 0; i < 4; ++i) {
        const unsigned short* Hc = hb[i & 1];
        unsigned short* Hn = hb[(i + 1) & 1];
        layer_fused<<<Npad / 16, 128, 0, stream>>>(rowptr, srcs, dinv, Hc,
                                                   Wt + (size_t)i * D * D,
                                                   bs + (size_t)i * D, Hn, dots, Wl,
                                                   N, (i == 3) ? 1 : 0);
    }

    // ---- mean pool (+bl) over fused per-node dots ----
    pool_graphs<<<NGRAPH, 256, 0, stream>>>(dots, batch, N, bl, (float*)d_out);
}

// Round 11
// 452.462 us; speedup vs baseline: 1.1509x; 1.0319x over previous
//
#include <hip/hip_runtime.h>

// ---------------------------------------------------------------------------
// GCN forward, reassociated: per layer h = relu( (A_hat h) W + b ).
// R23: 4 waves per 16-row tile -> 1 row per 16-lane group (chain floor).
// Wave-count ladder (same FETCH ~195MB, same gather loop):
//   R17 1 wave/tile: 80us, 2.9 TB/s, 10.9 waves/CU resident
//   R22 2 waves/tile: 72.5us, 3.1 TB/s, 12 waves/CU resident
// Nothing binds residency yet (VGPR 56, LDS 4.6K, thread cap 32 waves/CU)
// -> push the proven lever once more: 256-thread blocks per 16-row tile,
// 16 groups x 1 row, grid 6256 = 25024 waves (98/CU available, 8 blocks =
// 32 waves/CU thread-slot ceiling).
// Phase B: wave w computes column-tiles ct = 2w,2w+1 (disjoint out cols,
// shared LDS A-frags); layer-4 head dot: intra-wave shfl + 4-wave LDS
// reduce. Inner gather loop = R17/R22's proven masked batches, untouched.
// Kept: dedicated scale_x, packed pairs, CHUNK 2048, unpadded CSR.
// All layers pre-scaled (S = dinv*h). Epilogue folds bias+relu+output-dinv.
// NOTE: harness delivers int32 edge_index/batch.
// ---------------------------------------------------------------------------

constexpr int D = 128;
constexpr int NGRAPH = 512;
constexpr int CHUNK = 2048;       // edges per scatter block
constexpr int BSH = 9;            // 512 nodes per bucket
constexpr int OP = 136;           // out-tile pitch (ushorts): 272B, 16B-aligned rows

typedef __attribute__((ext_vector_type(8))) short bf16x8;
typedef __attribute__((ext_vector_type(4))) float f32x4;
typedef int i32x4u __attribute__((ext_vector_type(4), aligned(4)));

__device__ __forceinline__ float bf2f(unsigned short b) {
    return __uint_as_float(((unsigned int)b) << 16);
}
__device__ __forceinline__ unsigned short f2bf(float f) {   // round-to-nearest-even
    unsigned int u = __float_as_uint(f);
    u += 0x7FFFu + ((u >> 16) & 1u);
    return (unsigned short)(u >> 16);
}

// merged independent setup: [0,CB) cast x->bf16 | [CB,CB+256) cast W ->
// transposed bf16 Wt | [CB+256, ...) per-chunk bucket histogram.
__global__ __launch_bounds__(256) void setup_all(
        const float4* __restrict__ x4, ushort4* __restrict__ hb, int n4, int CB,
        const float* __restrict__ W, unsigned short* __restrict__ Wt,
        const int* __restrict__ ec, int E, int* __restrict__ bucketCnt) {
    __shared__ int h[256];
    const int t = threadIdx.x;
    const int b = blockIdx.x;
    if (b < CB) {
        int i = b * 256 + t;
        if (i < n4) {
            float4 v = x4[i];
            ushort4 o;
            o.x = f2bf(v.x); o.y = f2bf(v.y); o.z = f2bf(v.z); o.w = f2bf(v.w);
            hb[i] = o;
        }
    } else if (b < CB + 256) {
        int idx = (b - CB) * 256 + t;      // 4*128*128 = 65536 elems
        int i = idx >> 14;
        int rem = idx & 16383;
        int k = rem >> 7, c = rem & 127;
        Wt[(i << 14) + c * 128 + k] = f2bf(W[idx]);
    } else {
        h[t] = 0;
        __syncthreads();
        const int e0 = (b - CB - 256) * CHUNK;
        const int cnt = min(CHUNK, E - e0);
        for (int i = t; i < cnt; i += 256) atomicAdd(&h[ec[e0 + i] >> BSH], 1);
        __syncthreads();
        if (h[t]) atomicAdd(&bucketCnt[t], h[t]);
    }
}

// exclusive scan over 256 bucket counts -> bucketBase, globCursor
__global__ __launch_bounds__(256) void bucket_scan(const int* __restrict__ bucketCnt,
                                                   int* __restrict__ bucketBase,
                                                   int* __restrict__ globCursor) {
    __shared__ int s[256];
    const int t = threadIdx.x;
    int v = bucketCnt[t];
    s[t] = v; __syncthreads();
    for (int off = 1; off < 256; off <<= 1) {
        int x = (t >= off) ? s[t - off] : 0;
        __syncthreads();
        s[t] += x;
        __syncthreads();
    }
    int excl = s[t] - v;
    bucketBase[t] = excl;
    globCursor[t] = excl;
}

// scatter packed (r<<9 | c&511) into bucket-grouped array, LDS-staged
__global__ __launch_bounds__(256) void scatter_pairs(const int* __restrict__ er,
                                                     const int* __restrict__ ec, int E,
                                                     int* __restrict__ globCursor,
                                                     int* __restrict__ pairs) {
    __shared__ int h[256], lbase[256], cur[256], segd[256], s[256];
    __shared__ int stage[CHUNK];
    __shared__ unsigned char sb[CHUNK];
    const int t = threadIdx.x;
    const int e0 = blockIdx.x * CHUNK;
    const int cnt = min(CHUNK, E - e0);

    h[t] = 0;
    __syncthreads();
    for (int i = t; i < cnt; i += 256) atomicAdd(&h[ec[e0 + i] >> BSH], 1);
    __syncthreads();
    int v = h[t];
    s[t] = v; __syncthreads();
    for (int off = 1; off < 256; off <<= 1) {
        int x = (t >= off) ? s[t - off] : 0;
        __syncthreads();
        s[t] += x;
        __syncthreads();
    }
    lbase[t] = s[t] - v;
    cur[t] = s[t] - v;
    segd[t] = atomicAdd(&globCursor[t], v) - lbase[t];
    __syncthreads();
    for (int i = t; i < cnt; i += 256) {
        int c = ec[e0 + i];
        int b = c >> BSH;
        int p = atomicAdd(&cur[b], 1);
        stage[p] = (er[e0 + i] << BSH) | (c & 511);   // packed pair
        sb[p] = (unsigned char)b;
    }
    __syncthreads();
    for (int i = t; i < cnt; i += 256) {
        int b = sb[i];
        pairs[segd[b] + i] = stage[i];
    }
}

// one block per bucket. LDS hist+scan -> rowptr, dinv, slot fill. Unpadded.
__global__ __launch_bounds__(256) void fill_csr(const int* __restrict__ pairs,
                                                const int* __restrict__ bucketBase,
                                                const int* __restrict__ bucketCnt,
                                                int N, int E, int NBUCK,
                                                int* __restrict__ rowptr,
                                                float* __restrict__ dinv,
                                                int* __restrict__ srcs) {
    __shared__ int hist[512], lofs[512], s[256];
    const int t = threadIdx.x;
    const int b = blockIdx.x;
    const int c0 = b << BSH;
    const int base = bucketBase[b];
    const int cnt = bucketCnt[b];
    const int* pp = pairs + base;

    hist[t] = 0; hist[t + 256] = 0;
    __syncthreads();
    for (int i = t; i < cnt; i += 256) atomicAdd(&hist[pp[i] & 511], 1);
    __syncthreads();
    int a0 = hist[2 * t], a1 = hist[2 * t + 1];
    s[t] = a0 + a1; __syncthreads();
    for (int off = 1; off < 256; off <<= 1) {
        int x = (t >= off) ? s[t - off] : 0;
        __syncthreads();
        s[t] += x;
        __syncthreads();
    }
    int excl = s[t] - (a0 + a1);
    lofs[2 * t] = excl;
    lofs[2 * t + 1] = excl + a0;
    __syncthreads();
    const int nn = min(512, N - c0);
    for (int i = t; i < nn; i += 256) {
        rowptr[c0 + i] = base + lofs[i];
        dinv[c0 + i] = rsqrtf((float)hist[i] + 1.0f);
    }
    if (b == NBUCK - 1 && t == 0) rowptr[N] = E;
    __syncthreads();
    for (int i = t; i < cnt; i += 256) {
        int pr = pp[i];
        int p = atomicAdd(&lofs[pr & 511], 1);
        srcs[base + p] = pr >> BSH;
    }
}

// scale the bf16 x-cast by dinv in place (S = dinv * x):
// one uint4 (8 bf16) per thread, 16 uint4 per row.
__global__ __launch_bounds__(256) void scale_x(uint4* __restrict__ Hb0,
                                               const float* __restrict__ dinv,
                                               int nq) {                // nq = N*16
    int i = blockIdx.x * 256 + threadIdx.x;
    if (i >= nq) return;
    float dv = dinv[i >> 4];
    uint4 v = Hb0[i];
    unsigned int* p = (unsigned int*)&v;
#pragma unroll
    for (int k = 0; k < 4; ++k) {
        unsigned int d = p[k];
        unsigned short lo = f2bf(bf2f((unsigned short)(d & 0xFFFFu)) * dv);
        unsigned short hi = f2bf(bf2f((unsigned short)(d >> 16)) * dv);
        p[k] = ((unsigned int)hi << 16) | lo;
    }
    Hb0[i] = v;
}

// ---------------------------------------------------------------------------
// Fused layer: 256-thread block (4 waves) per 16-row tile.
// Phase A: 16 sixteen-lane groups (grp = wave*4+quad); group aggregates ONE
//   row (grp); lane owns one 16B chunk of the 256B row. R17's masked
//   8-edge batch loop (best measured). Inputs pre-scaled S = dinv*h.
//   P = dinv[row]*(sum S + S[row]) -> bf16, xor-swizzled A-tile.
// Phase B: barrier; all 4 waves load the same A-frags; barrier; wave w
//   computes column-tiles ct = 2w, 2w+1 (disjoint out columns). Epilogue
//   folds bias+relu+output-dinv into the shared out tile (pitch OP);
//   barrier; coalesced 16B readback+stores (1 chunk/thread).
//   Layer 4 (writeDots): intra-wave shfl reduce + 4-wave LDS reduce.
// C/D: col=lane&15, row=(lane>>4)*4+reg (verified mapping).
// ---------------------------------------------------------------------------
__global__ __launch_bounds__(256, 4) void layer_fused(
        const int* __restrict__ rowptr, const int* __restrict__ srcs,
        const float* __restrict__ dinv, const unsigned short* __restrict__ H,
        const unsigned short* __restrict__ Wt, const float* __restrict__ bias,
        unsigned short* __restrict__ Hn, float* __restrict__ dots,
        const float* __restrict__ Wl, int N, int writeDots) {
    __shared__ __align__(16) unsigned short U[16 * OP];   // 4.25 KB
    const int tid = threadIdx.x;         // 0..255
    const int wave = tid >> 6;           // 0..3
    const int lane = tid & 63;
    const int row16 = lane & 15;
    const int quad = lane >> 4;          // 0..3
    const int grp = wave * 4 + quad;     // 0..15
    const int r0 = blockIdx.x * 16;
    const bf16x8* H8 = (const bf16x8*)H;     // 16 chunks (16B) per row
    const int gl = row16;                    // chunk index this lane owns

    // ---- phase A: each group aggregates ITS row into swizzled A-tile ----
    {
        const int rt = grp;              // local row 0..15
        const int row = r0 + rt;
        float acc[8] = {0.f, 0.f, 0.f, 0.f, 0.f, 0.f, 0.f, 0.f};
        float sn = 0.f;
        if (row < N) {
            sn = dinv[row];
            int j = rowptr[row];
            const int end = rowptr[row + 1];
            // self-loop term (pre-scaled)
            bf16x8 hv = H8[(size_t)row * 16 + gl];
#pragma unroll
            for (int k = 0; k < 8; ++k) acc[k] = bf2f((unsigned short)hv[k]);
            const int ne = end - j;
            const int nb = (ne + 7) >> 3;     // masked 8-edge batches
            if (nb > 0) {
                i32x4u sA0, sA1, sB0, sB1;
                {   // srcs(0); srcs(1) issued BEFORE h(0)
                    const i32x4u* sp = (const i32x4u*)(srcs + j);
                    sA0 = sp[0]; sA1 = sp[1];
                }
                if (nb > 1) {
                    const i32x4u* sp = (const i32x4u*)(srcs + j + 8);
                    sB0 = sp[0]; sB1 = sp[1];
                }
                bf16x8 hc[8], hn[8];
#pragma unroll
                for (int t = 0; t < 8; ++t) {       // issue h(0)
                    int idx = (t < 4) ? sA0[t] : sA1[t - 4];
                    int rr = (t < ne) ? idx : row;
                    hc[t] = H8[(size_t)rr * 16 + gl];
                }
#pragma unroll 1
                for (int b = 0; b < nb; ++b) {
                    if (b + 1 < nb) {
                        const int remn = ne - (b + 1) * 8;
                        int rn[8];
#pragma unroll
                        for (int t = 0; t < 8; ++t) {   // waits srcs(b+1) only
                            int idx = (t < 4) ? sB0[t] : sB1[t - 4];
                            rn[t] = (t < remn) ? idx : row;
                        }
                        if (b + 2 < nb) {               // srcs(b+2) BEFORE h(b+1)
                            const i32x4u* sp = (const i32x4u*)(srcs + j + (b + 2) * 8);
                            sB0 = sp[0]; sB1 = sp[1];
                        }
#pragma unroll
                        for (int t = 0; t < 8; ++t)     // issue h(b+1)
                            hn[t] = H8[(size_t)rn[t] * 16 + gl];
                    }
                    // consume h(b); weight from remaining count
                    const int rem = ne - b * 8;
#pragma unroll
                    for (int t = 0; t < 8; ++t) {
                        const float w = (t < rem) ? 1.f : 0.f;
#pragma unroll
                        for (int k = 0; k < 8; ++k)
                            acc[k] = fmaf(w, bf2f((unsigned short)hc[t][k]), acc[k]);
                    }
#pragma unroll
                    for (int t = 0; t < 8; ++t) hc[t] = hn[t];
                }
            }
        }
        // P row (bf16) -> swizzled A-tile; rows >= N become zeros (sn=0)
        bf16x8 o;
#pragma unroll
        for (int k = 0; k < 8; ++k) o[k] = (short)f2bf(sn * acc[k]);
        *(bf16x8*)(U + rt * 128 + ((gl ^ rt) << 3)) = o;
    }
    __syncthreads();

    // ---- phase B: all waves load the same A fragments ----
    bf16x8 a0[4];
#pragma unroll
    for (int kc = 0; kc < 4; ++kc) {
        const int ph = (kc * 4 + quad) ^ row16;
        a0[kc] = *(const bf16x8*)(U + row16 * 128 + ph * 8);
    }
    __syncthreads();   // U is now reused as the out tile (pitch OP)

    // dinv of output rows (pre-scale stored features); not needed for dots
    float dv[4];
    if (!writeDots) {
#pragma unroll
        for (int i = 0; i < 4; ++i) {
            int ra = r0 + quad * 4 + i;
            dv[i] = (ra < N) ? dinv[ra] : 0.f;
        }
    }

    // wave w handles column-tiles ct = 2w, 2w+1
    float rd[4] = {0.f, 0.f, 0.f, 0.f};
#pragma unroll
    for (int c = 0; c < 2; ++c) {
        const int ct = wave * 2 + c;
        const int col = ct * 16 + row16;
        const bf16x8* wc = (const bf16x8*)(Wt + (size_t)col * 128);
        f32x4 acc0 = {0.f, 0.f, 0.f, 0.f};
#pragma unroll
        for (int kc = 0; kc < 4; ++kc) {
            const bf16x8 wf = wc[kc * 4 + quad];
            acc0 = __builtin_amdgcn_mfma_f32_16x16x32_bf16(a0[kc], wf, acc0, 0, 0, 0);
        }
        const float bv = bias[col];
        if (writeDots) {
            const float wl = Wl[col];
#pragma unroll
            for (int i = 0; i < 4; ++i) rd[i] += fmaxf(acc0[i] + bv, 0.f) * wl;
        } else {
#pragma unroll
            for (int i = 0; i < 4; ++i)
                U[(quad * 4 + i) * OP + col] = f2bf(dv[i] * fmaxf(acc0[i] + bv, 0.f));
        }
    }

    if (writeDots) {
        // intra-wave: sum over the 16 cols of each ct (lanes of same quad)
#pragma unroll
        for (int m = 1; m < 16; m <<= 1)
#pragma unroll
            for (int i = 0; i < 4; ++i) rd[i] += __shfl_xor(rd[i], m, 64);
        // cross-wave: partials via LDS (U reused as float scratch)
        float* R = (float*)U;
        if (row16 == 0) {
#pragma unroll
            for (int i = 0; i < 4; ++i) R[wave * 16 + quad * 4 + i] = rd[i];
        }
        __syncthreads();
        if (tid < 16) dots[r0 + tid] = R[tid] + R[16 + tid] + R[32 + tid] + R[48 + tid];
    } else {
        __syncthreads();
        // coalesced readback + store: 256 16B chunks, 1 per thread
        {
            int row = tid >> 4, c8 = tid & 15;
            bf16x8 v = *(const bf16x8*)(U + row * OP + c8 * 8);
            *(bf16x8*)(Hn + (size_t)(r0 + row) * 128 + c8 * 8) = v;
        }
    }
}

// one block per graph: binary-search node range in sorted batch, mean, +bl
__global__ __launch_bounds__(256) void pool_graphs(const float* __restrict__ dots,
                                                   const int* __restrict__ batch, int N,
                                                   const float* __restrict__ bl,
                                                   float* __restrict__ out) {
    __shared__ int bounds[2];
    __shared__ float red[4];
    const int g = blockIdx.x;
    const int t = threadIdx.x;
    if (t < 2) {
        int key = g + t;             // lower_bound(batch, key)
        int lo = 0, hi = N;
        while (lo < hi) {
            int mid = (lo + hi) >> 1;
            if (batch[mid] < key) lo = mid + 1; else hi = mid;
        }
        bounds[t] = lo;
    }
    __syncthreads();
    const int lo = bounds[0], hi = bounds[1];
    float s = 0.f;
    for (int i = lo + t; i < hi; i += 256) s += dots[i];
#pragma unroll
    for (int off = 32; off > 0; off >>= 1) s += __shfl_down(s, off, 64);
    if ((t & 63) == 0) red[t >> 6] = s;
    __syncthreads();
    if (t == 0) {
        float tot = red[0] + red[1] + red[2] + red[3];
        int cnt = hi - lo;
        out[g] = tot / (float)(cnt > 0 ? cnt : 1) + bl[0];
    }
}

extern "C" void kernel_launch(void* const* d_in, const int* in_sizes, int n_in,
                              void* d_out, int out_size, void* d_ws, size_t ws_size,
                              hipStream_t stream) {
    const float* x     = (const float*)d_in[0];
    const int*   eidx  = (const int*)d_in[1];    // int32 (harness converts int64)
    const int*   batch = (const int*)d_in[2];
    const float* Ws    = (const float*)d_in[3];
    const float* bs    = (const float*)d_in[4];
    const float* Wl    = (const float*)d_in[5];
    const float* bl    = (const float*)d_in[6];
    (void)n_in; (void)out_size;

    const int N = in_sizes[0] / D;
    const int E = in_sizes[1] / 2;
    const int* er = eidx;       // sources
    const int* ec = eidx + E;   // targets
    const int NBUCK = (N + 511) >> BSH;          // 512-node buckets (<= 256)
    const int NCHUNK = (E + CHUNK - 1) / CHUNK;

    // ---- workspace carve ----
    const int Npad = (N + 127) & ~127;
    const size_t hBytes = (size_t)Npad * D * sizeof(unsigned short); // 25.6 MB bf16
    auto al = [](size_t v) { return (v + 255) & ~(size_t)255; };
    char* base = (char*)d_ws;
    size_t off = 0;

    unsigned short* Hb0 = (unsigned short*)base; off = al(hBytes);
    int* bucketCnt  = (int*)(base + off);
    int* globCursor = bucketCnt + 256;
    off = al(off + 512 * sizeof(int));
    int*   bucketBase = (int*)(base + off);  off = al(off + 256 * sizeof(int));
    float* dinv   = (float*)(base + off);    off = al(off + (size_t)Npad * sizeof(float));
    float* dots   = (float*)(base + off);    off = al(off + (size_t)Npad * sizeof(float));
    int*   rowptr = (int*)(base + off);      off = al(off + (size_t)(Npad + 64) * sizeof(int));
    int*   srcs   = (int*)(base + off);      off = al(off + ((size_t)E + 64) * sizeof(int));
    unsigned short* Wt = (unsigned short*)(base + off);   off = al(off + 4 * 128 * 128 * sizeof(unsigned short));

    // second bf16 buffer: in ws if it fits, else reuse x's 51.2 MB input buffer
    // (Npad*256B <= N*512B, so the alias stays in-bounds). pairs aliases Hb1:
    // CSR build completes before layer-1 gemm writes Hb1 (same stream).
    const bool twoBuf = ws_size >= off + hBytes;
    unsigned short* Hb1 = twoBuf ? (unsigned short*)(base + off)
                                 : (unsigned short*)d_in[0];
    int* pairs = (int*)Hb1;
    unsigned short* hb[2] = { Hb0, Hb1 };

    // ---- setup: memset bucketCnt; merged cast_x | cast_W | histogram ----
    hipMemsetAsync(bucketCnt, 0, 256 * sizeof(int), stream);
    const int n4 = N * D / 4;
    const int CB = (n4 + 255) / 256;
    setup_all<<<CB + 256 + NCHUNK, 256, 0, stream>>>((const float4*)x, (ushort4*)Hb0,
                                                     n4, CB, Ws, Wt, ec, E, bucketCnt);

    // ---- binned CSR build (once; reused by all 4 layers) ----
    bucket_scan<<<1, 256, 0, stream>>>(bucketCnt, bucketBase, globCursor);
    scatter_pairs<<<NCHUNK, 256, 0, stream>>>(er, ec, E, globCursor, pairs);
    fill_csr<<<NBUCK, 256, 0, stream>>>(pairs, bucketBase, bucketCnt, N, E, NBUCK,
                                        rowptr, dinv, srcs);
    // ---- pre-scale x-cast by dinv (S = dinv*x) ----
    const int nq = N * 16;                       // uint4 per row = 16
    scale_x<<<(nq + 255) / 256, 256, 0, stream>>>((uint4*)Hb0, dinv, nq);

    // ---- 4 fused layers: aggregate -> LDS A-tile -> MFMA (-> head dot) ----
    for (int i = 0; i < 4; ++i) {
        const unsigned short* Hc = hb[i & 1];
        unsigned short* Hn = hb[(i + 1) & 1];
        layer_fused<<<Npad / 16, 256, 0, stream>>>(rowptr, srcs, dinv, Hc,
                                                   Wt + (size_t)i * D * D,
                                                   bs + (size_t)i * D, Hn, dots, Wl,
                                                   N, (i == 3) ? 1 : 0);
    }

    // ---- mean pool (+bl) over fused per-node dots ----
    pool_graphs<<<NGRAPH, 256, 0, stream>>>(dots, batch, N, bl, (float*)d_out);
}